// Round 4
// baseline (1944.199 us; speedup 1.0000x reference)
//
#include <hip/hip_runtime.h>
#include <hip/hip_bf16.h>

typedef unsigned short u16;
typedef unsigned int   u32;
typedef __attribute__((ext_vector_type(4))) float f32x4;
typedef __attribute__((ext_vector_type(8))) short s16x8;

__device__ __forceinline__ float b2f(u16 u){ u32 x = ((u32)u) << 16; return __builtin_bit_cast(float, x); }
__device__ __forceinline__ u16 f2b(float f){
  u32 x = __builtin_bit_cast(u32, f);
  u32 r = (x + 0x7FFFu + ((x >> 16) & 1u)) >> 16;
  return (u16)r;
}
// dual-dtype input readers: isbf=1 -> data stored as bf16, else fp32
__device__ __forceinline__ float inld(const void* p, size_t i, int isbf){
  return isbf ? b2f(((const u16*)p)[i]) : ((const float*)p)[i];
}
__device__ __forceinline__ u16 inld16(const void* p, size_t i, int isbf){
  return isbf ? ((const u16*)p)[i] : f2b(((const float*)p)[i]);
}

// ---------------- dtype detector: bits14-7 of u32 = exponent byte iff bf16 pair ----------------
__global__ __launch_bounds__(256) void detect_kernel(const u32* __restrict__ r5w, int* __restrict__ flag){
  __shared__ int cnt[2];
  int t = threadIdx.x;
  if (t < 2) cnt[t] = 0;
  __syncthreads();
  int inw = 0, nz = 0;
  for (int i = t; i < 16384; i += 256){
    u32 w = r5w[i];
    if (w == 0u) continue;
    u32 e = (w >> 7) & 0xFFu;
    nz++;
    if (e >= 0x58u && e <= 0x98u) inw++;
  }
  atomicAdd(&cnt[0], inw);
  atomicAdd(&cnt[1], nz);
  __syncthreads();
  if (t == 0) flag[0] = (2 * cnt[0] >= cnt[1]) ? 1 : 0;
}

// ---------------- prep: BN scale/bias, down_w pad, b4 canon, zero row ----------------
__global__ __launch_bounds__(256) void prep_kernel(
    const void* __restrict__ g, const void* __restrict__ be,
    const void* __restrict__ mn, const void* __restrict__ vr,
    const void* __restrict__ dw, const void* __restrict__ db,
    const void* __restrict__ b4, const int* __restrict__ flag,
    float* __restrict__ scale, float* __restrict__ bias,
    u16* __restrict__ dwp, float* __restrict__ dbp,
    u16* __restrict__ b4c, u16* __restrict__ zrow)
{
  const int isbf = *flag;
  int idx = blockIdx.x * 256 + threadIdx.x;
  if (idx < 512){
    float s = inld(g, idx, isbf) / sqrtf(inld(vr, idx, isbf) + 1e-5f);
    scale[idx] = s;
    bias[idx]  = inld(be, idx, isbf) - inld(mn, idx, isbf) * s;
  }
  if (idx < 128) dbp[idx] = (idx < 32) ? inld(db, idx, isbf) : 0.f;
  if (idx < 2048){
    zrow[idx] = 0;
    b4c[idx] = inld16(b4, idx, isbf);
  }
  if (idx < 128 * 2048){
    int j = idx >> 11;
    dwp[idx] = (j < 32) ? inld16(dw, idx, isbf) : (u16)0;
  }
}

// ---------------- pack fc0_w -> Wt[o, tap*2048 + i] ----------------
__global__ __launch_bounds__(256) void wt_pack(const void* __restrict__ w, const int* __restrict__ flag,
                                               u16* __restrict__ wt){
  const int isbf = *flag;
  int idx = blockIdx.x * 256 + threadIdx.x;
  if (idx >= 512 * 18432) return;
  int o = idx / 18432;
  int r = idx - o * 18432;
  int tap = r >> 11, i = r & 2047;
  wt[idx] = inld16(w, ((size_t)(o * 2048 + i)) * 9 + tap, isbf);
}

// ---------------- canonicalize conv4 weights ----------------
__global__ __launch_bounds__(256) void cvt_w4(const void* __restrict__ w4, const int* __restrict__ flag,
                                              u16* __restrict__ w4c){
  const int isbf = *flag;
  int idx = blockIdx.x * 256 + threadIdx.x;
  if (idx < 2048 * 4096) w4c[idx] = inld16(w4, idx, isbf);
}

// ---------------- transpose r5 [b,c,hw] -> r5nk [(b,hw), c] (pass-local, dual-dtype) ----------------
__global__ __launch_bounds__(256) void transpose_r5(const void* __restrict__ r5, size_t elem_off,
                                                    const int* __restrict__ flag, u16* __restrict__ r5nk){
  __shared__ u16 tile[64 * 197];
  const int isbf = *flag;
  int blk = blockIdx.x;            // NB b * 32 c-chunks
  int b = blk >> 5, c0 = (blk & 31) * 64;
  int t = threadIdx.x;
  size_t src = elem_off + ((size_t)b * 2048 + c0) * 196;
  for (int q = t; q < 64 * 196; q += 256){
    int cl = q / 196, hv = q - cl * 196;
    tile[cl * 197 + hv] = inld16(r5, src + q, isbf);
  }
  __syncthreads();
  for (int q = t; q < 64 * 196; q += 256){
    int hv = q >> 6, cl = q & 63;
    r5nk[((size_t)b * 196 + hv) * 2048 + c0 + cl] = tile[cl * 197 + hv];
  }
}

// ---------------- shared MFMA GEMM (C[n,o] = A_nk @ B[o,:]^T), row-guarded ----------------
// MODE 0: conv3x3  A=r5nk shifted/masked per tap, epi: scale/bias/relu -> u16, ldc=512
// MODE 1: dic      A=x1 (ldA=4096), epi: (+b4)*r5 -> xbA u16, ldc=2048
// MODE 2: c2       A dual: k<2048 -> xbA, else r5nk, epi: +b4 -> u16, ldc=2048
// MODE 3: down     A=c2 (ldA=2048), epi: +bias(f32) -> float, ldc=128
template<int MODE>
__global__ __launch_bounds__(256) void gemm_bt(
    const u16* __restrict__ Aptr, const u16* __restrict__ A2,
    const u16* __restrict__ Bw, void* __restrict__ Cout,
    const float* __restrict__ sc, const float* __restrict__ bi,
    const u16* __restrict__ bias16, const u16* __restrict__ zrow,
    int K, int ldA, int Mrows)
{
  __shared__ u16 As[128 * 32];
  __shared__ u16 Bs[128 * 32];
  const int tid = threadIdx.x;
  const int wv = tid >> 6, ln = tid & 63;
  const int m0 = blockIdx.x * 128;
  const int o0 = blockIdx.y * 128;

  const int row0 = tid >> 2;
  const int row1 = row0 + 64;
  const int kk = (tid & 3) * 8;

  int mAr[2];
  mAr[0] = m0 + row0; mAr[1] = m0 + row1;
  #pragma unroll
  for (int s = 0; s < 2; s++) if (mAr[s] >= Mrows) mAr[s] = Mrows - 1;

  int hA[2], vA[2];
  if constexpr (MODE == 0){
    #pragma unroll
    for (int s = 0; s < 2; s++){
      int hv = mAr[s] % 196;
      hA[s] = hv / 14; vA[s] = hv - hA[s] * 14;
    }
  }
  const u16* Brow0 = Bw + (size_t)(o0 + row0) * K + kk;
  const u16* Brow1 = Bw + (size_t)(o0 + row1) * K + kk;

  const int wm = (wv >> 1) * 64, wn = (wv & 1) * 64;
  const int fl = ln & 15, fq = ln >> 4;

  f32x4 acc[4][4];
  #pragma unroll
  for (int i = 0; i < 4; i++)
    #pragma unroll
    for (int j = 0; j < 4; j++) acc[i][j] = (f32x4){0.f, 0.f, 0.f, 0.f};

  for (int k0 = 0; k0 < K; k0 += 32){
    const u16 *ga0, *ga1;
    if constexpr (MODE == 0){
      int tap = k0 >> 11;
      int kin = (k0 & 2047) + kk;
      int dy = tap / 3 - 1, dx = tap - (tap / 3) * 3 - 1;
      int dlt = dy * 14 + dx;
      bool ok0 = ((unsigned)(hA[0] + dy) < 14u) && ((unsigned)(vA[0] + dx) < 14u);
      bool ok1 = ((unsigned)(hA[1] + dy) < 14u) && ((unsigned)(vA[1] + dx) < 14u);
      ga0 = ok0 ? Aptr + (size_t)(mAr[0] + dlt) * 2048 + kin : zrow + kk;
      ga1 = ok1 ? Aptr + (size_t)(mAr[1] + dlt) * 2048 + kin : zrow + kk;
    } else if constexpr (MODE == 2){
      const u16* base = (k0 < 2048) ? Aptr : A2;
      int kin = (k0 & 2047) + kk;
      ga0 = base + (size_t)mAr[0] * 2048 + kin;
      ga1 = base + (size_t)mAr[1] * 2048 + kin;
    } else {
      ga0 = Aptr + (size_t)mAr[0] * ldA + k0 + kk;
      ga1 = Aptr + (size_t)mAr[1] * ldA + k0 + kk;
    }
    uint4 a0 = *(const uint4*)ga0;
    uint4 a1 = *(const uint4*)ga1;
    uint4 b0 = *(const uint4*)(Brow0 + k0);
    uint4 b1 = *(const uint4*)(Brow1 + k0);

    __syncthreads();
    *(uint4*)&As[row0 * 32 + kk] = a0;
    *(uint4*)&As[row1 * 32 + kk] = a1;
    *(uint4*)&Bs[row0 * 32 + kk] = b0;
    *(uint4*)&Bs[row1 * 32 + kk] = b1;
    __syncthreads();

    s16x8 af[4], bfr[4];
    #pragma unroll
    for (int i = 0; i < 4; i++)
      af[i] = *(const s16x8*)&As[(wm + i * 16 + fl) * 32 + fq * 8];
    #pragma unroll
    for (int j = 0; j < 4; j++)
      bfr[j] = *(const s16x8*)&Bs[(wn + j * 16 + fl) * 32 + fq * 8];
    #pragma unroll
    for (int i = 0; i < 4; i++)
      #pragma unroll
      for (int j = 0; j < 4; j++)
        acc[i][j] = __builtin_amdgcn_mfma_f32_16x16x32_bf16(af[i], bfr[j], acc[i][j], 0, 0, 0);
  }

  #pragma unroll
  for (int i = 0; i < 4; i++){
    int mrow = m0 + wm + i * 16 + fq * 4;
    #pragma unroll
    for (int j = 0; j < 4; j++){
      int o = o0 + wn + j * 16 + fl;
      f32x4 a = acc[i][j];
      #pragma unroll
      for (int r = 0; r < 4; r++){
        int n = mrow + r;
        if (n >= Mrows) continue;
        float v = a[r];
        if constexpr (MODE == 0){
          v = fmaxf(v * sc[o] + bi[o], 0.f);
          ((u16*)Cout)[(size_t)n * 512 + o] = f2b(v);
        } else if constexpr (MODE == 1){
          v += b2f(bias16[o]);
          v *= b2f(A2[(size_t)n * 2048 + o]);
          ((u16*)Cout)[(size_t)n * 2048 + o] = f2b(v);
        } else if constexpr (MODE == 2){
          v += b2f(bias16[o]);
          ((u16*)Cout)[(size_t)n * 2048 + o] = f2b(v);
        } else {
          ((float*)Cout)[(size_t)n * 128 + o] = v + bi[o];
        }
      }
    }
  }
}

// ---------------- EM attention: one block per (pass-local) batch ----------------
__global__ __launch_bounds__(512) void em_kernel(
    const u16* __restrict__ x, const void* __restrict__ mu0, const int* __restrict__ flag,
    u16* __restrict__ x2, float* __restrict__ zg)
{
  __shared__ float mu[512][8];
  __shared__ float zz[196][8];
  __shared__ float part[64][8];
  __shared__ float red8[8];
  const int isbf = *flag;
  const int b = blockIdx.x;
  const int t = threadIdx.x;
  const u16* xb = x + (size_t)b * 196 * 512;

  for (int q = t; q < 4096; q += 512) mu[q >> 3][q & 7] = inld(mu0, q, isbf);
  __syncthreads();
  { int k = t & 7, g = t >> 3; float s = 0;
    for (int c = g; c < 512; c += 64){ float m = mu[c][k]; s += m * m; }
    part[g][k] = s; }
  __syncthreads();
  if (t < 8){ float s = 0; for (int g = 0; g < 64; g++) s += part[g][t]; red8[t] = sqrtf(s) + 1e-6f; }
  __syncthreads();
  for (int q = t; q < 4096; q += 512) mu[q >> 3][q & 7] /= red8[q & 7];
  __syncthreads();

  for (int it = 0; it < 3; it++){
    for (int p = t; p < 1568; p += 512){
      int n = p >> 3, k = p & 7;
      const u16* xr = xb + n * 512;
      float s = 0;
      for (int c = 0; c < 512; c += 8){
        uint4 u = *(const uint4*)(xr + c);
        s += b2f((u16)(u.x & 0xffff)) * mu[c][k]     + b2f((u16)(u.x >> 16)) * mu[c + 1][k]
           + b2f((u16)(u.y & 0xffff)) * mu[c + 2][k] + b2f((u16)(u.y >> 16)) * mu[c + 3][k]
           + b2f((u16)(u.z & 0xffff)) * mu[c + 4][k] + b2f((u16)(u.z >> 16)) * mu[c + 5][k]
           + b2f((u16)(u.w & 0xffff)) * mu[c + 6][k] + b2f((u16)(u.w >> 16)) * mu[c + 7][k];
      }
      zz[n][k] = s;
    }
    __syncthreads();
    if (t < 196){
      float mx = zz[t][0];
      #pragma unroll
      for (int k = 1; k < 8; k++) mx = fmaxf(mx, zz[t][k]);
      float e[8], sm = 0;
      #pragma unroll
      for (int k = 0; k < 8; k++){ e[k] = expf(zz[t][k] - mx); sm += e[k]; }
      #pragma unroll
      for (int k = 0; k < 8; k++) zz[t][k] = e[k] / sm;
    }
    __syncthreads();
    { int k = t & 7, g = t >> 3; float s = 0;
      for (int n = g; n < 196; n += 64) s += zz[n][k];
      part[g][k] = s; }
    __syncthreads();
    if (t < 8){ float s = 0; for (int g = 0; g < 64; g++) s += part[g][t]; red8[t] = s + 1e-6f; }
    __syncthreads();
    for (int q = t; q < 4096; q += 512){
      int c = q >> 3, k = q & 7;
      float s = 0;
      for (int n = 0; n < 196; n++) s += b2f(xb[n * 512 + c]) * zz[n][k];
      mu[c][k] = s / red8[k];
    }
    __syncthreads();
    { int k = t & 7, g = t >> 3; float s = 0;
      for (int c = g; c < 512; c += 64){ float m = mu[c][k]; s += m * m; }
      part[g][k] = s; }
    __syncthreads();
    if (t < 8){ float s = 0; for (int g = 0; g < 64; g++) s += part[g][t]; red8[t] = sqrtf(s) + 1e-6f; }
    __syncthreads();
    for (int q = t; q < 4096; q += 512) mu[q >> 3][q & 7] /= red8[q & 7];
    __syncthreads();
  }

  for (int p = t; p < 1568; p += 512) zg[b * 1568 + p] = zz[p >> 3][p & 7];
  for (int q = t; q < 196 * 512; q += 512){
    int n = q >> 9, c = q & 511;
    float xr = 0;
    #pragma unroll
    for (int k = 0; k < 8; k++) xr += mu[c][k] * zz[n][k];
    float v = b2f(xb[n * 512 + c]) + xr;
    x2[(size_t)b * 196 * 512 + q] = f2b(fmaxf(v, 0.f));
  }
}

// ---------------- expand: x1[n, k*512+c] = sum_w x2 * z_t ----------------
__global__ __launch_bounds__(256) void expand_kernel(
    const u16* __restrict__ x2, const float* __restrict__ zg, u16* __restrict__ x1)
{
  __shared__ u16 xs[14 * 512];
  __shared__ float zb[196 * 8];
  int bh = blockIdx.x;          // NB*14
  int b = bh / 14, h = bh - b * 14;
  int t = threadIdx.x;
  const u16* src = x2 + ((size_t)b * 196 + h * 14) * 512;
  for (int q = t; q < 14 * 512; q += 256) xs[q] = src[q];
  for (int q = t; q < 1568; q += 256) zb[q] = zg[b * 1568 + q];
  __syncthreads();
  size_t outbase = ((size_t)b * 196 + h * 14) * 4096;
  for (int q = t; q < 14 * 4096; q += 256){
    int v = q >> 12, kc = q & 4095;
    int k = kc >> 9, c = kc & 511;
    float s = 0;
    #pragma unroll
    for (int w = 0; w < 14; w++)
      s += b2f(xs[w * 512 + c]) * zb[(w * 14 + v) * 8 + k];
    x1[outbase + q] = f2b(s);
  }
}

// ---------------- pooling: xg (dual-dtype output) ----------------
__global__ __launch_bounds__(256) void pool_xg(
    const float* __restrict__ xd, const int* __restrict__ flag,
    float* __restrict__ g32, void* __restrict__ outbase, int elem_off)
{
  __shared__ float part[8][32];
  int b = blockIdx.x, t = threadIdx.x;
  int j = t & 31, g = t >> 5;
  float s = 0;
  for (int hv = g; hv < 196; hv += 8)
    s += xd[((size_t)b * 196 + hv) * 128 + j];
  part[g][j] = s;
  __syncthreads();
  if (t < 32){
    float s2 = 0;
    #pragma unroll
    for (int g2 = 0; g2 < 8; g2++) s2 += part[g2][t];
    part[0][t] = s2 * (1.f / 196.f);
  }
  __syncthreads();
  if (t < 8){
    float v = 0.25f * (part[0][4 * t] + part[0][4 * t + 1] + part[0][4 * t + 2] + part[0][4 * t + 3]);
    g32[b * 8 + t] = v;
    int o = elem_off + b * 8 + t;
    if (*flag) ((u16*)outbase)[o] = f2b(v);
    else       ((float*)outbase)[o] = v;
  }
}

// ---------------- final: xc, GAPs, classifier (dual-dtype in/out) ----------------
__global__ __launch_bounds__(256) void final_kernel(
    const float* __restrict__ xd, const float* __restrict__ g32,
    const u16* __restrict__ r5nk, const void* __restrict__ clsw,
    const void* __restrict__ clsb, const int* __restrict__ flag,
    void* __restrict__ outbase, int elem_off)
{
  __shared__ float xc[196];
  __shared__ float red[8];
  const int isbf = *flag;
  int b = blockIdx.x, t = threadIdx.x;
  if (t < 196){
    float s = 0;
    const float* row = xd + ((size_t)b * 196 + t) * 128;
    #pragma unroll
    for (int j = 0; j < 32; j++) s += row[j] * g32[b * 8 + (j >> 2)];
    xc[t] = s * (1.f / 32.f);
  }
  if (t < 8) red[t] = 0.f;
  __syncthreads();
  float s1[8], s2[8];
  #pragma unroll
  for (int ci = 0; ci < 8; ci++){ s1[ci] = 0.f; s2[ci] = 0.f; }
  for (int hv = 0; hv < 196; hv++){
    const u16* row = r5nk + ((size_t)b * 196 + hv) * 2048;
    float xcv = xc[hv];
    #pragma unroll
    for (int ci = 0; ci < 8; ci++){
      float v = b2f(row[t + ci * 256]);
      s1[ci] += v; s2[ci] += v * xcv;
    }
  }
  float pm[8];
  #pragma unroll
  for (int m = 0; m < 8; m++) pm[m] = 0.f;
  #pragma unroll
  for (int ci = 0; ci < 8; ci++){
    int c = t + ci * 256;
    float a1 = s1[ci] * (1.f / 196.f), a2 = s2[ci] * (1.f / 196.f);
    #pragma unroll
    for (int m = 0; m < 8; m++)
      pm[m] += inld(clsw, m * 4096 + c, isbf) * a1 + inld(clsw, m * 4096 + 2048 + c, isbf) * a2;
  }
  #pragma unroll
  for (int m = 0; m < 8; m++) atomicAdd(&red[m], pm[m]);
  __syncthreads();
  if (t < 8){
    float v = red[t] + inld(clsb, t, isbf);
    int o = elem_off + b * 8 + t;
    if (isbf) ((u16*)outbase)[o] = f2b(v);
    else      ((float*)outbase)[o] = v;
  }
}

extern "C" void kernel_launch(void* const* d_in, const int* in_sizes, int n_in,
                              void* d_out, int out_size, void* d_ws, size_t ws_size,
                              hipStream_t stream)
{
  (void)in_sizes; (void)n_in; (void)out_size;
  const void* r5  = d_in[0];
  const void* fcw = d_in[1];
  const void* bng = d_in[2];
  const void* bnb = d_in[3];
  const void* bnm = d_in[4];
  const void* bnv = d_in[5];
  const void* mu0 = d_in[6];
  const void* w4  = d_in[7];
  const void* b4  = d_in[8];
  const void* dw  = d_in[9];
  const void* db  = d_in[10];
  const void* cw  = d_in[11];
  const void* cb  = d_in[12];

  // ---- choose batches-per-pass from ws_size ----
  auto foot = [](int nb)->size_t{
    return 42ull * 1024 * 1024 + (size_t)nb * 3670016ull;
  };
  int NB = 4;
  if (foot(64) <= ws_size) NB = 64;
  else if (foot(32) <= ws_size) NB = 32;
  else if (foot(16) <= ws_size) NB = 16;
  else if (foot(8) <= ws_size) NB = 8;
  const int rowsP = NB * 196;
  const int tiles = (rowsP + 127) / 128;
  const int passes = 64 / NB;

  char* base = (char*)d_ws;
  size_t off = 0;
  auto take = [&](size_t bytes)->char*{
    char* r = base + off;
    off = (off + bytes + 255) & ~(size_t)255;
    return r;
  };

  int*   flag = (int*)  take(256);
  float* scale= (float*)take(512 * 4);
  float* bias = (float*)take(512 * 4);
  float* dbp  = (float*)take(128 * 4);
  u16*   zrow = (u16*)  take(2048 * 2);
  u16*   b4c  = (u16*)  take(2048 * 2);
  float* g32  = (float*)take(64 * 8 * 4);
  u16*   dwp  = (u16*)  take(128 * 2048 * 2);
  float* zg   = (float*)take(64ULL * 1568 * 4);
  u16*   Wt   = (u16*)  take(512ULL * 18432 * 2);          // conv3x3 weights, packed
  u16*   w4c  = (u16*)  take(2048ULL * 4096 * 2);          // conv4 weights, canonical bf16
  u16*   r5nk = (u16*)  take((size_t)rowsP * 2048 * 2);    // per-pass [n, c]
  u16*   regX = (u16*)  take((size_t)rowsP * 4096 * 2);    // x1 -> c2
  u16*   bufC = (u16*)  take((size_t)rowsP * 2048 * 2);    // xnk -> xbA
  u16*   x2b  = (u16*)  take((size_t)rowsP * 512 * 2);
  float* xd   = (float*)take((size_t)rowsP * 128 * 4);

  u16* x1  = regX;
  u16* c2  = regX;
  u16* xnk = bufC;
  u16* xbA = bufC;

  detect_kernel<<<1, 256, 0, stream>>>((const u32*)r5, flag);
  prep_kernel<<<1024, 256, 0, stream>>>(bng, bnb, bnm, bnv, dw, db, b4, flag,
                                        scale, bias, dwp, dbp, b4c, zrow);
  wt_pack<<<(512 * 18432 + 255) / 256, 256, 0, stream>>>(fcw, flag, Wt);
  cvt_w4<<<(2048 * 4096) / 256, 256, 0, stream>>>(w4, flag, w4c);

  for (int p = 0; p < passes; p++){
    size_t r5off = (size_t)p * NB * 2048 * 196;
    int oxg = p * NB * 8;
    int oo2 = 512 + p * NB * 8;

    transpose_r5<<<NB * 32, 256, 0, stream>>>(r5, r5off, flag, r5nk);
    gemm_bt<0><<<dim3(tiles, 4), 256, 0, stream>>>(r5nk, nullptr, Wt, xnk, scale, bias, nullptr, zrow, 18432, 2048, rowsP);
    em_kernel<<<NB, 512, 0, stream>>>(xnk, mu0, flag, x2b, zg);
    expand_kernel<<<NB * 14, 256, 0, stream>>>(x2b, zg, x1);
    gemm_bt<1><<<dim3(tiles, 16), 256, 0, stream>>>(x1, r5nk, w4c, xbA, nullptr, nullptr, b4c, zrow, 4096, 4096, rowsP);
    gemm_bt<2><<<dim3(tiles, 16), 256, 0, stream>>>(xbA, r5nk, w4c, c2, nullptr, nullptr, b4c, zrow, 4096, 2048, rowsP);
    gemm_bt<3><<<dim3(tiles, 1), 256, 0, stream>>>(c2, nullptr, dwp, xd, nullptr, dbp, nullptr, zrow, 2048, 2048, rowsP);
    pool_xg<<<NB, 256, 0, stream>>>(xd, flag, g32, d_out, oxg);
    final_kernel<<<NB, 256, 0, stream>>>(xd, g32, r5nk, cw, cb, flag, d_out, oo2);
  }
}

// Round 5
// 1835.676 us; speedup vs baseline: 1.0591x; 1.0591x over previous
//
#include <hip/hip_runtime.h>
#include <hip/hip_bf16.h>

typedef unsigned short u16;
typedef unsigned int   u32;
typedef __attribute__((ext_vector_type(4))) float f32x4;
typedef __attribute__((ext_vector_type(8))) short s16x8;

__device__ __forceinline__ float b2f(u16 u){ u32 x = ((u32)u) << 16; return __builtin_bit_cast(float, x); }
__device__ __forceinline__ u16 f2b(float f){
  u32 x = __builtin_bit_cast(u32, f);
  u32 r = (x + 0x7FFFu + ((x >> 16) & 1u)) >> 16;
  return (u16)r;
}
// dual-dtype input readers: isbf=1 -> data stored as bf16, else fp32
__device__ __forceinline__ float inld(const void* p, size_t i, int isbf){
  return isbf ? b2f(((const u16*)p)[i]) : ((const float*)p)[i];
}
__device__ __forceinline__ u16 inld16(const void* p, size_t i, int isbf){
  return isbf ? ((const u16*)p)[i] : f2b(((const float*)p)[i]);
}

__device__ __forceinline__ void async16(const void* g, void* l){
  __builtin_amdgcn_global_load_lds((const __attribute__((address_space(1))) void*)g,
                                   (__attribute__((address_space(3))) void*)l, 16, 0, 0);
}

// ---------------- dtype detector: bits14-7 of u32 = exponent byte iff bf16 pair ----------------
__global__ __launch_bounds__(256) void detect_kernel(const u32* __restrict__ r5w, int* __restrict__ flag){
  __shared__ int cnt[2];
  int t = threadIdx.x;
  if (t < 2) cnt[t] = 0;
  __syncthreads();
  int inw = 0, nz = 0;
  for (int i = t; i < 16384; i += 256){
    u32 w = r5w[i];
    if (w == 0u) continue;
    u32 e = (w >> 7) & 0xFFu;
    nz++;
    if (e >= 0x58u && e <= 0x98u) inw++;
  }
  atomicAdd(&cnt[0], inw);
  atomicAdd(&cnt[1], nz);
  __syncthreads();
  if (t == 0) flag[0] = (2 * cnt[0] >= cnt[1]) ? 1 : 0;
}

// ---------------- prep: BN scale/bias, down_w pad, b4 canon, zero row ----------------
__global__ __launch_bounds__(256) void prep_kernel(
    const void* __restrict__ g, const void* __restrict__ be,
    const void* __restrict__ mn, const void* __restrict__ vr,
    const void* __restrict__ dw, const void* __restrict__ db,
    const void* __restrict__ b4, const int* __restrict__ flag,
    float* __restrict__ scale, float* __restrict__ bias,
    u16* __restrict__ dwp, float* __restrict__ dbp,
    u16* __restrict__ b4c, u16* __restrict__ zrow)
{
  const int isbf = *flag;
  int idx = blockIdx.x * 256 + threadIdx.x;
  if (idx < 512){
    float s = inld(g, idx, isbf) / sqrtf(inld(vr, idx, isbf) + 1e-5f);
    scale[idx] = s;
    bias[idx]  = inld(be, idx, isbf) - inld(mn, idx, isbf) * s;
  }
  if (idx < 128) dbp[idx] = (idx < 32) ? inld(db, idx, isbf) : 0.f;
  if (idx < 2048){
    zrow[idx] = 0;
    b4c[idx] = inld16(b4, idx, isbf);
  }
  if (idx < 128 * 2048){
    int j = idx >> 11;
    dwp[idx] = (j < 32) ? inld16(dw, idx, isbf) : (u16)0;
  }
}

// ---------------- pack fc0_w -> Wt[o, tap*2048 + i] ----------------
__global__ __launch_bounds__(256) void wt_pack(const void* __restrict__ w, const int* __restrict__ flag,
                                               u16* __restrict__ wt){
  const int isbf = *flag;
  int idx = blockIdx.x * 256 + threadIdx.x;
  if (idx >= 512 * 18432) return;
  int o = idx / 18432;
  int r = idx - o * 18432;
  int tap = r >> 11, i = r & 2047;
  wt[idx] = inld16(w, ((size_t)(o * 2048 + i)) * 9 + tap, isbf);
}

// ---------------- canonicalize conv4 weights ----------------
__global__ __launch_bounds__(256) void cvt_w4(const void* __restrict__ w4, const int* __restrict__ flag,
                                              u16* __restrict__ w4c){
  const int isbf = *flag;
  int idx = blockIdx.x * 256 + threadIdx.x;
  if (idx < 2048 * 4096) w4c[idx] = inld16(w4, idx, isbf);
}

// ---------------- transpose r5 [b,c,hw] -> r5nk [(b,hw), c] (pass-local, dual-dtype) ----------------
__global__ __launch_bounds__(256) void transpose_r5(const void* __restrict__ r5, size_t elem_off,
                                                    const int* __restrict__ flag, u16* __restrict__ r5nk){
  __shared__ u16 tile[64 * 197];
  const int isbf = *flag;
  int blk = blockIdx.x;            // NB b * 32 c-chunks
  int b = blk >> 5, c0 = (blk & 31) * 64;
  int t = threadIdx.x;
  size_t src = elem_off + ((size_t)b * 2048 + c0) * 196;
  for (int q = t; q < 64 * 196; q += 256){
    int cl = q / 196, hv = q - cl * 196;
    tile[cl * 197 + hv] = inld16(r5, src + q, isbf);
  }
  __syncthreads();
  for (int q = t; q < 64 * 196; q += 256){
    int hv = q >> 6, cl = q & 63;
    r5nk[((size_t)b * 196 + hv) * 2048 + c0 + cl] = tile[cl * 197 + hv];
  }
}

// ---------------- shared MFMA GEMM (C[n,o] = A_nk @ B[o,:]^T), async16 staging ----------------
// MODE 0: conv3x3  A=r5nk shifted/masked per tap, epi: scale/bias/relu -> u16, ldc=512
// MODE 1: dic      A=x1 (ldA=4096), epi: (+b4)*r5 -> xbA u16, ldc=2048  [swapped grid]
// MODE 2: c2       A dual: k<2048 -> xbA, else r5nk, epi: +b4 -> u16, ldc=2048  [swapped grid]
// MODE 3: down     A=c2 (ldA=2048), epi: +bias(f32) -> float, ldc=128
template<int MODE>
__global__ __launch_bounds__(256) void gemm_bt(
    const u16* __restrict__ Aptr, const u16* __restrict__ A2,
    const u16* __restrict__ Bw, void* __restrict__ Cout,
    const float* __restrict__ sc, const float* __restrict__ bi,
    const u16* __restrict__ bias16, const u16* __restrict__ zrow,
    int K, int ldA, int Mrows)
{
  constexpr bool SWAPG = (MODE == 1 || MODE == 2);   // o-tile fastest for L2 A-reuse
  __shared__ u16 As[128 * 32];
  __shared__ u16 Bs[128 * 32];
  const int tid = threadIdx.x;
  const int wv = tid >> 6, ln = tid & 63;
  const int m0 = (SWAPG ? blockIdx.y : blockIdx.x) * 128;
  const int o0 = (SWAPG ? blockIdx.x : blockIdx.y) * 128;

  // staging: wave wv covers rows wv*32..wv*32+31 of A and B tiles.
  // lane ln -> row wv*32+(ln>>2) (+16 for second load), k-slice (ln&3)*8.
  // LDS dest = wave-uniform base + lane*16B == row*32+(ln&3)*8 elements. (HW constraint OK)
  const int rowA0 = wv * 32 + (ln >> 2);
  const int kofs  = (ln & 3) * 8;
  int mA0 = m0 + rowA0, mA1 = mA0 + 16;
  if (mA0 >= Mrows) mA0 = Mrows - 1;
  if (mA1 >= Mrows) mA1 = Mrows - 1;
  const int oB0 = o0 + rowA0, oB1 = oB0 + 16;

  int h0 = 0, v0 = 0, h1 = 0, v1 = 0;
  if constexpr (MODE == 0){
    int hv0 = mA0 % 196; h0 = hv0 / 14; v0 = hv0 - h0 * 14;
    int hv1 = mA1 % 196; h1 = hv1 / 14; v1 = hv1 - h1 * 14;
  }

  const int wm = (wv >> 1) * 64, wn = (wv & 1) * 64;
  const int fl = ln & 15, fq = ln >> 4;

  f32x4 acc[4][4];
  #pragma unroll
  for (int i = 0; i < 4; i++)
    #pragma unroll
    for (int j = 0; j < 4; j++) acc[i][j] = (f32x4){0.f, 0.f, 0.f, 0.f};

  u16* ldsA0 = &As[wv * 1024];
  u16* ldsA1 = &As[wv * 1024 + 512];
  u16* ldsB0 = &Bs[wv * 1024];
  u16* ldsB1 = &Bs[wv * 1024 + 512];

  for (int k0 = 0; k0 < K; k0 += 32){
    const u16 *ga0, *ga1;
    if constexpr (MODE == 0){
      int tap = k0 >> 11;
      int kin = (k0 & 2047) + kofs;
      int dy = tap / 3 - 1, dx = tap - (tap / 3) * 3 - 1;
      int dlt = dy * 14 + dx;
      bool ok0 = ((unsigned)(h0 + dy) < 14u) && ((unsigned)(v0 + dx) < 14u);
      bool ok1 = ((unsigned)(h1 + dy) < 14u) && ((unsigned)(v1 + dx) < 14u);
      ga0 = ok0 ? Aptr + (size_t)(mA0 + dlt) * 2048 + kin : zrow + kofs;
      ga1 = ok1 ? Aptr + (size_t)(mA1 + dlt) * 2048 + kin : zrow + kofs;
    } else if constexpr (MODE == 2){
      const u16* base = (k0 < 2048) ? Aptr : A2;
      int kin = (k0 & 2047) + kofs;
      ga0 = base + (size_t)mA0 * 2048 + kin;
      ga1 = base + (size_t)mA1 * 2048 + kin;
    } else {
      ga0 = Aptr + (size_t)mA0 * ldA + k0 + kofs;
      ga1 = Aptr + (size_t)mA1 * ldA + k0 + kofs;
    }
    const u16* gb0 = Bw + (size_t)oB0 * K + k0 + kofs;
    const u16* gb1 = Bw + (size_t)oB1 * K + k0 + kofs;

    async16(ga0, ldsA0);
    async16(ga1, ldsA1);
    async16(gb0, ldsB0);
    async16(gb1, ldsB1);
    __syncthreads();   // drains vmcnt -> LDS tiles complete & visible

    s16x8 af[4], bfr[4];
    #pragma unroll
    for (int i = 0; i < 4; i++)
      af[i] = *(const s16x8*)&As[(wm + i * 16 + fl) * 32 + fq * 8];
    #pragma unroll
    for (int j = 0; j < 4; j++)
      bfr[j] = *(const s16x8*)&Bs[(wn + j * 16 + fl) * 32 + fq * 8];
    #pragma unroll
    for (int i = 0; i < 4; i++)
      #pragma unroll
      for (int j = 0; j < 4; j++)
        acc[i][j] = __builtin_amdgcn_mfma_f32_16x16x32_bf16(af[i], bfr[j], acc[i][j], 0, 0, 0);
    __syncthreads();   // all reads done before next stage overwrites LDS
  }

  #pragma unroll
  for (int i = 0; i < 4; i++){
    int mrow = m0 + wm + i * 16 + fq * 4;
    #pragma unroll
    for (int j = 0; j < 4; j++){
      int o = o0 + wn + j * 16 + fl;
      f32x4 a = acc[i][j];
      #pragma unroll
      for (int r = 0; r < 4; r++){
        int n = mrow + r;
        if (n >= Mrows) continue;
        float v = a[r];
        if constexpr (MODE == 0){
          v = fmaxf(v * sc[o] + bi[o], 0.f);
          ((u16*)Cout)[(size_t)n * 512 + o] = f2b(v);
        } else if constexpr (MODE == 1){
          v += b2f(bias16[o]);
          v *= b2f(A2[(size_t)n * 2048 + o]);
          ((u16*)Cout)[(size_t)n * 2048 + o] = f2b(v);
        } else if constexpr (MODE == 2){
          v += b2f(bias16[o]);
          ((u16*)Cout)[(size_t)n * 2048 + o] = f2b(v);
        } else {
          ((float*)Cout)[(size_t)n * 128 + o] = v + bi[o];
        }
      }
    }
  }
}

// ---------------- EM attention: one block per (pass-local) batch ----------------
__global__ __launch_bounds__(512) void em_kernel(
    const u16* __restrict__ x, const void* __restrict__ mu0, const int* __restrict__ flag,
    u16* __restrict__ x2, float* __restrict__ zg)
{
  __shared__ float mu[512][9];     // pad 8->9: conflict-free column access
  __shared__ float zz[196][9];
  __shared__ float part[64][8];
  __shared__ float red8[8];
  const int isbf = *flag;
  const int b = blockIdx.x;
  const int t = threadIdx.x;
  const u16* xb = x + (size_t)b * 196 * 512;

  for (int q = t; q < 4096; q += 512) mu[q >> 3][q & 7] = inld(mu0, q, isbf);
  __syncthreads();
  { int k = t & 7, g = t >> 3; float s = 0;
    for (int c = g; c < 512; c += 64){ float m = mu[c][k]; s += m * m; }
    part[g][k] = s; }
  __syncthreads();
  if (t < 8){ float s = 0; for (int g = 0; g < 64; g++) s += part[g][t]; red8[t] = sqrtf(s) + 1e-6f; }
  __syncthreads();
  for (int q = t; q < 4096; q += 512) mu[q >> 3][q & 7] /= red8[q & 7];
  __syncthreads();

  for (int it = 0; it < 3; it++){
    // scores z = softmax_k(x^T mu)
    for (int p = t; p < 1568; p += 512){
      int n = p >> 3, k = p & 7;
      const u16* xr = xb + n * 512;
      float s = 0;
      for (int c = 0; c < 512; c += 8){
        uint4 u = *(const uint4*)(xr + c);
        s += b2f((u16)(u.x & 0xffff)) * mu[c][k]     + b2f((u16)(u.x >> 16)) * mu[c + 1][k]
           + b2f((u16)(u.y & 0xffff)) * mu[c + 2][k] + b2f((u16)(u.y >> 16)) * mu[c + 3][k]
           + b2f((u16)(u.z & 0xffff)) * mu[c + 4][k] + b2f((u16)(u.z >> 16)) * mu[c + 5][k]
           + b2f((u16)(u.w & 0xffff)) * mu[c + 6][k] + b2f((u16)(u.w >> 16)) * mu[c + 7][k];
      }
      zz[n][k] = s;
    }
    __syncthreads();
    if (t < 196){
      float mx = zz[t][0];
      #pragma unroll
      for (int k = 1; k < 8; k++) mx = fmaxf(mx, zz[t][k]);
      float e[8], sm = 0;
      #pragma unroll
      for (int k = 0; k < 8; k++){ e[k] = expf(zz[t][k] - mx); sm += e[k]; }
      #pragma unroll
      for (int k = 0; k < 8; k++) zz[t][k] = e[k] / sm;
    }
    __syncthreads();
    { int k = t & 7, g = t >> 3; float s = 0;
      for (int n = g; n < 196; n += 64) s += zz[n][k];
      part[g][k] = s; }
    __syncthreads();
    if (t < 8){ float s = 0; for (int g = 0; g < 64; g++) s += part[g][t]; red8[t] = s + 1e-6f; }
    __syncthreads();
    // mu[c][k] = (sum_n x[n,c] zz[n,k]) / red8[k] -- thread-per-channel, coalesced x reads
    {
      int c = t;  // 512 threads == 512 channels
      float s[8];
      #pragma unroll
      for (int k = 0; k < 8; k++) s[k] = 0.f;
      for (int n = 0; n < 196; n++){
        float xv = b2f(xb[n * 512 + c]);
        #pragma unroll
        for (int k = 0; k < 8; k++) s[k] += xv * zz[n][k];   // broadcast LDS read
      }
      __syncthreads();   // all reads of old mu done (none) / ensure zz stable
      #pragma unroll
      for (int k = 0; k < 8; k++) mu[c][k] = s[k] / red8[k];
    }
    __syncthreads();
    { int k = t & 7, g = t >> 3; float s = 0;
      for (int c = g; c < 512; c += 64){ float m = mu[c][k]; s += m * m; }
      part[g][k] = s; }
    __syncthreads();
    if (t < 8){ float s = 0; for (int g = 0; g < 64; g++) s += part[g][t]; red8[t] = sqrtf(s) + 1e-6f; }
    __syncthreads();
    for (int q = t; q < 4096; q += 512) mu[q >> 3][q & 7] /= red8[q & 7];
    __syncthreads();
  }

  for (int p = t; p < 1568; p += 512) zg[b * 1568 + p] = zz[p >> 3][p & 7];
  for (int q = t; q < 196 * 512; q += 512){
    int n = q >> 9, c = q & 511;
    float xr = 0;
    #pragma unroll
    for (int k = 0; k < 8; k++) xr += mu[c][k] * zz[n][k];
    float v = b2f(xb[n * 512 + c]) + xr;
    x2[(size_t)b * 196 * 512 + q] = f2b(fmaxf(v, 0.f));
  }
}

// ---------------- expand: x1[n, k*512+c] = sum_w x2 * z_t ----------------
__global__ __launch_bounds__(256) void expand_kernel(
    const u16* __restrict__ x2, const float* __restrict__ zg, u16* __restrict__ x1)
{
  __shared__ u16 xs[14 * 512];
  __shared__ float zb[196 * 8];
  int bh = blockIdx.x;          // NB*14
  int b = bh / 14, h = bh - b * 14;
  int t = threadIdx.x;
  const u16* src = x2 + ((size_t)b * 196 + h * 14) * 512;
  for (int q = t; q < 14 * 512; q += 256) xs[q] = src[q];
  for (int q = t; q < 1568; q += 256) zb[q] = zg[b * 1568 + q];
  __syncthreads();
  size_t outbase = ((size_t)b * 196 + h * 14) * 4096;
  for (int q = t; q < 14 * 4096; q += 256){
    int v = q >> 12, kc = q & 4095;
    int k = kc >> 9, c = kc & 511;
    float s = 0;
    #pragma unroll
    for (int w = 0; w < 14; w++)
      s += b2f(xs[w * 512 + c]) * zb[(w * 14 + v) * 8 + k];
    x1[outbase + q] = f2b(s);
  }
}

// ---------------- pooling: xg (dual-dtype output) ----------------
__global__ __launch_bounds__(256) void pool_xg(
    const float* __restrict__ xd, const int* __restrict__ flag,
    float* __restrict__ g32, void* __restrict__ outbase, int elem_off)
{
  __shared__ float part[8][32];
  int b = blockIdx.x, t = threadIdx.x;
  int j = t & 31, g = t >> 5;
  float s = 0;
  for (int hv = g; hv < 196; hv += 8)
    s += xd[((size_t)b * 196 + hv) * 128 + j];
  part[g][j] = s;
  __syncthreads();
  if (t < 32){
    float s2 = 0;
    #pragma unroll
    for (int g2 = 0; g2 < 8; g2++) s2 += part[g2][t];
    part[0][t] = s2 * (1.f / 196.f);
  }
  __syncthreads();
  if (t < 8){
    float v = 0.25f * (part[0][4 * t] + part[0][4 * t + 1] + part[0][4 * t + 2] + part[0][4 * t + 3]);
    g32[b * 8 + t] = v;
    int o = elem_off + b * 8 + t;
    if (*flag) ((u16*)outbase)[o] = f2b(v);
    else       ((float*)outbase)[o] = v;
  }
}

// ---------------- final: xc, GAPs, classifier (dual-dtype in/out) ----------------
__global__ __launch_bounds__(256) void final_kernel(
    const float* __restrict__ xd, const float* __restrict__ g32,
    const u16* __restrict__ r5nk, const void* __restrict__ clsw,
    const void* __restrict__ clsb, const int* __restrict__ flag,
    void* __restrict__ outbase, int elem_off)
{
  __shared__ float xc[196];
  __shared__ float red[8];
  const int isbf = *flag;
  int b = blockIdx.x, t = threadIdx.x;
  if (t < 196){
    float s = 0;
    const float* row = xd + ((size_t)b * 196 + t) * 128;
    #pragma unroll
    for (int j = 0; j < 32; j++) s += row[j] * g32[b * 8 + (j >> 2)];
    xc[t] = s * (1.f / 32.f);
  }
  if (t < 8) red[t] = 0.f;
  __syncthreads();
  float s1[8], s2[8];
  #pragma unroll
  for (int ci = 0; ci < 8; ci++){ s1[ci] = 0.f; s2[ci] = 0.f; }
  for (int hv = 0; hv < 196; hv++){
    const u16* row = r5nk + ((size_t)b * 196 + hv) * 2048;
    float xcv = xc[hv];
    #pragma unroll
    for (int ci = 0; ci < 8; ci++){
      float v = b2f(row[t + ci * 256]);
      s1[ci] += v; s2[ci] += v * xcv;
    }
  }
  float pm[8];
  #pragma unroll
  for (int m = 0; m < 8; m++) pm[m] = 0.f;
  #pragma unroll
  for (int ci = 0; ci < 8; ci++){
    int c = t + ci * 256;
    float a1 = s1[ci] * (1.f / 196.f), a2 = s2[ci] * (1.f / 196.f);
    #pragma unroll
    for (int m = 0; m < 8; m++)
      pm[m] += inld(clsw, m * 4096 + c, isbf) * a1 + inld(clsw, m * 4096 + 2048 + c, isbf) * a2;
  }
  #pragma unroll
  for (int m = 0; m < 8; m++) atomicAdd(&red[m], pm[m]);
  __syncthreads();
  if (t < 8){
    float v = red[t] + inld(clsb, t, isbf);
    int o = elem_off + b * 8 + t;
    if (isbf) ((u16*)outbase)[o] = f2b(v);
    else      ((float*)outbase)[o] = v;
  }
}

extern "C" void kernel_launch(void* const* d_in, const int* in_sizes, int n_in,
                              void* d_out, int out_size, void* d_ws, size_t ws_size,
                              hipStream_t stream)
{
  (void)in_sizes; (void)n_in; (void)out_size;
  const void* r5  = d_in[0];
  const void* fcw = d_in[1];
  const void* bng = d_in[2];
  const void* bnb = d_in[3];
  const void* bnm = d_in[4];
  const void* bnv = d_in[5];
  const void* mu0 = d_in[6];
  const void* w4  = d_in[7];
  const void* b4  = d_in[8];
  const void* dw  = d_in[9];
  const void* db  = d_in[10];
  const void* cw  = d_in[11];
  const void* cb  = d_in[12];

  // ---- choose batches-per-pass from ws_size ----
  auto foot = [](int nb)->size_t{
    return 42ull * 1024 * 1024 + (size_t)nb * 3670016ull;
  };
  int NB = 4;
  if (foot(64) <= ws_size) NB = 64;
  else if (foot(32) <= ws_size) NB = 32;
  else if (foot(16) <= ws_size) NB = 16;
  else if (foot(8) <= ws_size) NB = 8;
  const int rowsP = NB * 196;
  const int tiles = (rowsP + 127) / 128;
  const int passes = 64 / NB;

  char* base = (char*)d_ws;
  size_t off = 0;
  auto take = [&](size_t bytes)->char*{
    char* r = base + off;
    off = (off + bytes + 255) & ~(size_t)255;
    return r;
  };

  int*   flag = (int*)  take(256);
  float* scale= (float*)take(512 * 4);
  float* bias = (float*)take(512 * 4);
  float* dbp  = (float*)take(128 * 4);
  u16*   zrow = (u16*)  take(2048 * 2);
  u16*   b4c  = (u16*)  take(2048 * 2);
  float* g32  = (float*)take(64 * 8 * 4);
  u16*   dwp  = (u16*)  take(128 * 2048 * 2);
  float* zg   = (float*)take(64ULL * 1568 * 4);
  u16*   Wt   = (u16*)  take(512ULL * 18432 * 2);          // conv3x3 weights, packed
  u16*   w4c  = (u16*)  take(2048ULL * 4096 * 2);          // conv4 weights, canonical bf16
  u16*   r5nk = (u16*)  take((size_t)rowsP * 2048 * 2);    // per-pass [n, c]
  u16*   regX = (u16*)  take((size_t)rowsP * 4096 * 2);    // x1 -> c2
  u16*   bufC = (u16*)  take((size_t)rowsP * 2048 * 2);    // xnk -> xbA
  u16*   x2b  = (u16*)  take((size_t)rowsP * 512 * 2);
  float* xd   = (float*)take((size_t)rowsP * 128 * 4);

  u16* x1  = regX;
  u16* c2  = regX;
  u16* xnk = bufC;
  u16* xbA = bufC;

  detect_kernel<<<1, 256, 0, stream>>>((const u32*)r5, flag);
  prep_kernel<<<1024, 256, 0, stream>>>(bng, bnb, bnm, bnv, dw, db, b4, flag,
                                        scale, bias, dwp, dbp, b4c, zrow);
  wt_pack<<<(512 * 18432 + 255) / 256, 256, 0, stream>>>(fcw, flag, Wt);
  cvt_w4<<<(2048 * 4096) / 256, 256, 0, stream>>>(w4, flag, w4c);

  for (int p = 0; p < passes; p++){
    size_t r5off = (size_t)p * NB * 2048 * 196;
    int oxg = p * NB * 8;
    int oo2 = 512 + p * NB * 8;

    transpose_r5<<<NB * 32, 256, 0, stream>>>(r5, r5off, flag, r5nk);
    gemm_bt<0><<<dim3(tiles, 4), 256, 0, stream>>>(r5nk, nullptr, Wt, xnk, scale, bias, nullptr, zrow, 18432, 2048, rowsP);
    em_kernel<<<NB, 512, 0, stream>>>(xnk, mu0, flag, x2b, zg);
    expand_kernel<<<NB * 14, 256, 0, stream>>>(x2b, zg, x1);
    gemm_bt<1><<<dim3(16, tiles), 256, 0, stream>>>(x1, r5nk, w4c, xbA, nullptr, nullptr, b4c, zrow, 4096, 4096, rowsP);
    gemm_bt<2><<<dim3(16, tiles), 256, 0, stream>>>(xbA, r5nk, w4c, c2, nullptr, nullptr, b4c, zrow, 4096, 2048, rowsP);
    gemm_bt<3><<<dim3(tiles, 1), 256, 0, stream>>>(c2, nullptr, dwp, xd, nullptr, dbp, nullptr, zrow, 2048, 2048, rowsP);
    pool_xg<<<NB, 256, 0, stream>>>(xd, flag, g32, d_out, oxg);
    final_kernel<<<NB, 256, 0, stream>>>(xd, g32, r5nk, cw, cb, flag, d_out, oo2);
  }
}

// Round 6
// 1687.403 us; speedup vs baseline: 1.1522x; 1.0879x over previous
//
#include <hip/hip_runtime.h>
#include <hip/hip_bf16.h>

typedef unsigned short u16;
typedef unsigned int   u32;
typedef __attribute__((ext_vector_type(4))) float f32x4;
typedef __attribute__((ext_vector_type(8))) short s16x8;

__device__ __forceinline__ float b2f(u16 u){ u32 x = ((u32)u) << 16; return __builtin_bit_cast(float, x); }
__device__ __forceinline__ u16 f2b(float f){
  u32 x = __builtin_bit_cast(u32, f);
  u32 r = (x + 0x7FFFu + ((x >> 16) & 1u)) >> 16;
  return (u16)r;
}
// dual-dtype input readers: isbf=1 -> data stored as bf16, else fp32
__device__ __forceinline__ float inld(const void* p, size_t i, int isbf){
  return isbf ? b2f(((const u16*)p)[i]) : ((const float*)p)[i];
}
__device__ __forceinline__ u16 inld16(const void* p, size_t i, int isbf){
  return isbf ? ((const u16*)p)[i] : f2b(((const float*)p)[i]);
}

__device__ __forceinline__ void async16(const void* g, void* l){
  __builtin_amdgcn_global_load_lds((const __attribute__((address_space(1))) void*)g,
                                   (__attribute__((address_space(3))) void*)l, 16, 0, 0);
}

// ---------------- dtype detector: bits14-7 of u32 = exponent byte iff bf16 pair ----------------
__global__ __launch_bounds__(256) void detect_kernel(const u32* __restrict__ r5w, int* __restrict__ flag){
  __shared__ int cnt[2];
  int t = threadIdx.x;
  if (t < 2) cnt[t] = 0;
  __syncthreads();
  int inw = 0, nz = 0;
  for (int i = t; i < 16384; i += 256){
    u32 w = r5w[i];
    if (w == 0u) continue;
    u32 e = (w >> 7) & 0xFFu;
    nz++;
    if (e >= 0x58u && e <= 0x98u) inw++;
  }
  atomicAdd(&cnt[0], inw);
  atomicAdd(&cnt[1], nz);
  __syncthreads();
  if (t == 0) flag[0] = (2 * cnt[0] >= cnt[1]) ? 1 : 0;
}

// ---------------- prep: BN scale/bias, down_w pad, b4 canon, zero row ----------------
__global__ __launch_bounds__(256) void prep_kernel(
    const void* __restrict__ g, const void* __restrict__ be,
    const void* __restrict__ mn, const void* __restrict__ vr,
    const void* __restrict__ dw, const void* __restrict__ db,
    const void* __restrict__ b4, const int* __restrict__ flag,
    float* __restrict__ scale, float* __restrict__ bias,
    u16* __restrict__ dwp, float* __restrict__ dbp,
    u16* __restrict__ b4c, u16* __restrict__ zrow)
{
  const int isbf = *flag;
  int idx = blockIdx.x * 256 + threadIdx.x;
  if (idx < 512){
    float s = inld(g, idx, isbf) / sqrtf(inld(vr, idx, isbf) + 1e-5f);
    scale[idx] = s;
    bias[idx]  = inld(be, idx, isbf) - inld(mn, idx, isbf) * s;
  }
  if (idx < 128) dbp[idx] = (idx < 32) ? inld(db, idx, isbf) : 0.f;
  if (idx < 2048){
    zrow[idx] = 0;
    b4c[idx] = inld16(b4, idx, isbf);
  }
  if (idx < 128 * 2048){
    int j = idx >> 11;
    dwp[idx] = (j < 32) ? inld16(dw, idx, isbf) : (u16)0;
  }
}

// ---------------- pack fc0_w -> Wt[o, tap*2048 + i] ----------------
__global__ __launch_bounds__(256) void wt_pack(const void* __restrict__ w, const int* __restrict__ flag,
                                               u16* __restrict__ wt){
  const int isbf = *flag;
  int idx = blockIdx.x * 256 + threadIdx.x;
  if (idx >= 512 * 18432) return;
  int o = idx / 18432;
  int r = idx - o * 18432;
  int tap = r >> 11, i = r & 2047;
  wt[idx] = inld16(w, ((size_t)(o * 2048 + i)) * 9 + tap, isbf);
}

// ---------------- canonicalize conv4 weights ----------------
__global__ __launch_bounds__(256) void cvt_w4(const void* __restrict__ w4, const int* __restrict__ flag,
                                              u16* __restrict__ w4c){
  const int isbf = *flag;
  int idx = blockIdx.x * 256 + threadIdx.x;
  if (idx < 2048 * 4096) w4c[idx] = inld16(w4, idx, isbf);
}

// ---------------- transpose r5 [b,c,hw] -> r5nk [(b,hw), c] (pass-local, dual-dtype) ----------------
__global__ __launch_bounds__(256) void transpose_r5(const void* __restrict__ r5, size_t elem_off,
                                                    const int* __restrict__ flag, u16* __restrict__ r5nk){
  __shared__ u16 tile[64 * 197];
  const int isbf = *flag;
  int blk = blockIdx.x;            // NB b * 32 c-chunks
  int b = blk >> 5, c0 = (blk & 31) * 64;
  int t = threadIdx.x;
  size_t src = elem_off + ((size_t)b * 2048 + c0) * 196;
  for (int q = t; q < 64 * 196; q += 256){
    int cl = q / 196, hv = q - cl * 196;
    tile[cl * 197 + hv] = inld16(r5, src + q, isbf);
  }
  __syncthreads();
  for (int q = t; q < 64 * 196; q += 256){
    int hv = q >> 6, cl = q & 63;
    r5nk[((size_t)b * 196 + hv) * 2048 + c0 + cl] = tile[cl * 197 + hv];
  }
}

// ---------------- shared MFMA GEMM (C[n,o] = A_nk @ B[o,:]^T) ----------------
// BK=64, async16 staging (128B/row segments), XOR k-chunk swizzle for conflict-free ds_read_b128.
// MODE 0: conv3x3  A=r5nk shifted/masked per tap, epi: scale/bias/relu -> u16, ldc=512
// MODE 1: dic      A=x1 (ldA=4096), epi: (+b4)*r5 -> xbA u16, ldc=2048  [swapped grid]
// MODE 2: c2       A dual: k<2048 -> xbA, else r5nk, epi: +b4 -> u16, ldc=2048  [swapped grid]
// MODE 3: down     A=c2 (ldA=2048), epi: +bias(f32) -> float, ldc=128
template<int MODE>
__global__ __launch_bounds__(256) void gemm_bt(
    const u16* __restrict__ Aptr, const u16* __restrict__ A2,
    const u16* __restrict__ Bw, void* __restrict__ Cout,
    const float* __restrict__ sc, const float* __restrict__ bi,
    const u16* __restrict__ bias16, const u16* __restrict__ zrow,
    int K, int ldA, int Mrows)
{
  constexpr bool SWAPG = (MODE == 1 || MODE == 2);   // o-tile fastest for L2 A-reuse
  __shared__ u16 As[128 * 64];   // 16 KB
  __shared__ u16 Bs[128 * 64];   // 16 KB
  const int tid = threadIdx.x;
  const int wv = tid >> 6, ln = tid & 63;
  const int m0 = (SWAPG ? blockIdx.y : blockIdx.x) * 128;
  const int o0 = (SWAPG ? blockIdx.x : blockIdx.y) * 128;

  // staging: wave wv covers tile rows wv*32 .. wv*32+31, four calls of 8 rows each.
  // lane ln -> row sub = ln>>3 within the 8-row group; k-chunk kq = (ln&7) XOR sub (swizzle).
  // LDS dest = wave-uniform base + lane*16B  ->  row-major position (ln&7); content = chunk kq.
  const int sub = ln >> 3;
  const int kq  = (ln & 7) ^ sub;
  const int kofs = kq * 8;

  int mA[4];
  int hA[4], vA[4];
  int oB[4];
  #pragma unroll
  for (int i = 0; i < 4; i++){
    int r = m0 + wv * 32 + i * 8 + sub;
    if (r >= Mrows) r = Mrows - 1;
    mA[i] = r;
    if constexpr (MODE == 0){
      int hv = r % 196;
      hA[i] = hv / 14; vA[i] = hv - hA[i] * 14;
    }
    oB[i] = o0 + wv * 32 + i * 8 + sub;
  }

  const int wm = (wv >> 1) * 64, wn = (wv & 1) * 64;
  const int fl = ln & 15, fq = ln >> 4;
  const int fl7 = fl & 7;

  f32x4 acc[4][4];
  #pragma unroll
  for (int i = 0; i < 4; i++)
    #pragma unroll
    for (int j = 0; j < 4; j++) acc[i][j] = (f32x4){0.f, 0.f, 0.f, 0.f};

  for (int k0 = 0; k0 < K; k0 += 64){
    #pragma unroll
    for (int i = 0; i < 4; i++){
      const u16* ga;
      if constexpr (MODE == 0){
        int tap = k0 >> 11;
        int kin = (k0 & 2047) + kofs;
        int dy = tap / 3 - 1, dx = tap - (tap / 3) * 3 - 1;
        int dlt = dy * 14 + dx;
        bool ok = ((unsigned)(hA[i] + dy) < 14u) && ((unsigned)(vA[i] + dx) < 14u);
        ga = ok ? Aptr + (size_t)(mA[i] + dlt) * 2048 + kin : zrow + kofs;
      } else if constexpr (MODE == 2){
        const u16* base = (k0 < 2048) ? Aptr : A2;
        int kin = (k0 & 2047) + kofs;
        ga = base + (size_t)mA[i] * 2048 + kin;
      } else {
        ga = Aptr + (size_t)mA[i] * ldA + k0 + kofs;
      }
      async16(ga, &As[wv * 2048 + i * 512]);
    }
    #pragma unroll
    for (int i = 0; i < 4; i++){
      const u16* gb = Bw + (size_t)oB[i] * K + k0 + kofs;
      async16(gb, &Bs[wv * 2048 + i * 512]);
    }
    __syncthreads();   // drains vmcnt -> LDS tiles complete & visible

    #pragma unroll
    for (int s = 0; s < 2; s++){
      const int pos = ((fq + 4 * s) ^ fl7) * 8;
      s16x8 af[4], bfr[4];
      #pragma unroll
      for (int i = 0; i < 4; i++)
        af[i] = *(const s16x8*)&As[(wm + i * 16 + fl) * 64 + pos];
      #pragma unroll
      for (int j = 0; j < 4; j++)
        bfr[j] = *(const s16x8*)&Bs[(wn + j * 16 + fl) * 64 + pos];
      #pragma unroll
      for (int i = 0; i < 4; i++)
        #pragma unroll
        for (int j = 0; j < 4; j++)
          acc[i][j] = __builtin_amdgcn_mfma_f32_16x16x32_bf16(af[i], bfr[j], acc[i][j], 0, 0, 0);
    }
    __syncthreads();   // all reads done before next stage overwrites LDS
  }

  #pragma unroll
  for (int i = 0; i < 4; i++){
    int mrow = m0 + wm + i * 16 + fq * 4;
    #pragma unroll
    for (int j = 0; j < 4; j++){
      int o = o0 + wn + j * 16 + fl;
      f32x4 a = acc[i][j];
      #pragma unroll
      for (int r = 0; r < 4; r++){
        int n = mrow + r;
        if (n >= Mrows) continue;
        float v = a[r];
        if constexpr (MODE == 0){
          v = fmaxf(v * sc[o] + bi[o], 0.f);
          ((u16*)Cout)[(size_t)n * 512 + o] = f2b(v);
        } else if constexpr (MODE == 1){
          v += b2f(bias16[o]);
          v *= b2f(A2[(size_t)n * 2048 + o]);
          ((u16*)Cout)[(size_t)n * 2048 + o] = f2b(v);
        } else if constexpr (MODE == 2){
          v += b2f(bias16[o]);
          ((u16*)Cout)[(size_t)n * 2048 + o] = f2b(v);
        } else {
          ((float*)Cout)[(size_t)n * 128 + o] = v + bi[o];
        }
      }
    }
  }
}

// ---------------- EM attention: one block per (pass-local) batch ----------------
__global__ __launch_bounds__(512) void em_kernel(
    const u16* __restrict__ x, const void* __restrict__ mu0, const int* __restrict__ flag,
    u16* __restrict__ x2, float* __restrict__ zg)
{
  __shared__ float mu[512][9];     // pad 8->9: conflict-free column access
  __shared__ float zz[196][9];
  __shared__ float part[64][8];
  __shared__ float red8[8];
  const int isbf = *flag;
  const int b = blockIdx.x;
  const int t = threadIdx.x;
  const u16* xb = x + (size_t)b * 196 * 512;

  for (int q = t; q < 4096; q += 512) mu[q >> 3][q & 7] = inld(mu0, q, isbf);
  __syncthreads();
  { int k = t & 7, g = t >> 3; float s = 0;
    for (int c = g; c < 512; c += 64){ float m = mu[c][k]; s += m * m; }
    part[g][k] = s; }
  __syncthreads();
  if (t < 8){ float s = 0; for (int g = 0; g < 64; g++) s += part[g][t]; red8[t] = sqrtf(s) + 1e-6f; }
  __syncthreads();
  for (int q = t; q < 4096; q += 512) mu[q >> 3][q & 7] /= red8[q & 7];
  __syncthreads();

  for (int it = 0; it < 3; it++){
    for (int p = t; p < 1568; p += 512){
      int n = p >> 3, k = p & 7;
      const u16* xr = xb + n * 512;
      float s = 0;
      for (int c = 0; c < 512; c += 8){
        uint4 u = *(const uint4*)(xr + c);
        s += b2f((u16)(u.x & 0xffff)) * mu[c][k]     + b2f((u16)(u.x >> 16)) * mu[c + 1][k]
           + b2f((u16)(u.y & 0xffff)) * mu[c + 2][k] + b2f((u16)(u.y >> 16)) * mu[c + 3][k]
           + b2f((u16)(u.z & 0xffff)) * mu[c + 4][k] + b2f((u16)(u.z >> 16)) * mu[c + 5][k]
           + b2f((u16)(u.w & 0xffff)) * mu[c + 6][k] + b2f((u16)(u.w >> 16)) * mu[c + 7][k];
      }
      zz[n][k] = s;
    }
    __syncthreads();
    if (t < 196){
      float mx = zz[t][0];
      #pragma unroll
      for (int k = 1; k < 8; k++) mx = fmaxf(mx, zz[t][k]);
      float e[8], sm = 0;
      #pragma unroll
      for (int k = 0; k < 8; k++){ e[k] = expf(zz[t][k] - mx); sm += e[k]; }
      #pragma unroll
      for (int k = 0; k < 8; k++) zz[t][k] = e[k] / sm;
    }
    __syncthreads();
    { int k = t & 7, g = t >> 3; float s = 0;
      for (int n = g; n < 196; n += 64) s += zz[n][k];
      part[g][k] = s; }
    __syncthreads();
    if (t < 8){ float s = 0; for (int g = 0; g < 64; g++) s += part[g][t]; red8[t] = s + 1e-6f; }
    __syncthreads();
    {
      int c = t;
      float s[8];
      #pragma unroll
      for (int k = 0; k < 8; k++) s[k] = 0.f;
      for (int n = 0; n < 196; n++){
        float xv = b2f(xb[n * 512 + c]);
        #pragma unroll
        for (int k = 0; k < 8; k++) s[k] += xv * zz[n][k];
      }
      __syncthreads();
      #pragma unroll
      for (int k = 0; k < 8; k++) mu[c][k] = s[k] / red8[k];
    }
    __syncthreads();
    { int k = t & 7, g = t >> 3; float s = 0;
      for (int c = g; c < 512; c += 64){ float m = mu[c][k]; s += m * m; }
      part[g][k] = s; }
    __syncthreads();
    if (t < 8){ float s = 0; for (int g = 0; g < 64; g++) s += part[g][t]; red8[t] = sqrtf(s) + 1e-6f; }
    __syncthreads();
    for (int q = t; q < 4096; q += 512) mu[q >> 3][q & 7] /= red8[q & 7];
    __syncthreads();
  }

  for (int p = t; p < 1568; p += 512) zg[b * 1568 + p] = zz[p >> 3][p & 7];
  for (int q = t; q < 196 * 512; q += 512){
    int n = q >> 9, c = q & 511;
    float xr = 0;
    #pragma unroll
    for (int k = 0; k < 8; k++) xr += mu[c][k] * zz[n][k];
    float v = b2f(xb[n * 512 + c]) + xr;
    x2[(size_t)b * 196 * 512 + q] = f2b(fmaxf(v, 0.f));
  }
}

// ---------------- expand: x1[n, k*512+c] = sum_w x2 * z_t ----------------
__global__ __launch_bounds__(256) void expand_kernel(
    const u16* __restrict__ x2, const float* __restrict__ zg, u16* __restrict__ x1)
{
  __shared__ u16 xs[14 * 512];
  __shared__ float zb[196 * 8];
  int bh = blockIdx.x;          // NB*14
  int b = bh / 14, h = bh - b * 14;
  int t = threadIdx.x;
  const u16* src = x2 + ((size_t)b * 196 + h * 14) * 512;
  for (int q = t; q < 14 * 512; q += 256) xs[q] = src[q];
  for (int q = t; q < 1568; q += 256) zb[q] = zg[b * 1568 + q];
  __syncthreads();
  size_t outbase = ((size_t)b * 196 + h * 14) * 4096;
  for (int q = t; q < 14 * 4096; q += 256){
    int v = q >> 12, kc = q & 4095;
    int k = kc >> 9, c = kc & 511;
    float s = 0;
    #pragma unroll
    for (int w = 0; w < 14; w++)
      s += b2f(xs[w * 512 + c]) * zb[(w * 14 + v) * 8 + k];
    x1[outbase + q] = f2b(s);
  }
}

// ---------------- pooling: xg (dual-dtype output) ----------------
__global__ __launch_bounds__(256) void pool_xg(
    const float* __restrict__ xd, const int* __restrict__ flag,
    float* __restrict__ g32, void* __restrict__ outbase, int elem_off)
{
  __shared__ float part[8][32];
  int b = blockIdx.x, t = threadIdx.x;
  int j = t & 31, g = t >> 5;
  float s = 0;
  for (int hv = g; hv < 196; hv += 8)
    s += xd[((size_t)b * 196 + hv) * 128 + j];
  part[g][j] = s;
  __syncthreads();
  if (t < 32){
    float s2 = 0;
    #pragma unroll
    for (int g2 = 0; g2 < 8; g2++) s2 += part[g2][t];
    part[0][t] = s2 * (1.f / 196.f);
  }
  __syncthreads();
  if (t < 8){
    float v = 0.25f * (part[0][4 * t] + part[0][4 * t + 1] + part[0][4 * t + 2] + part[0][4 * t + 3]);
    g32[b * 8 + t] = v;
    int o = elem_off + b * 8 + t;
    if (*flag) ((u16*)outbase)[o] = f2b(v);
    else       ((float*)outbase)[o] = v;
  }
}

// ---------------- final: xc, GAPs, classifier (dual-dtype in/out) ----------------
__global__ __launch_bounds__(256) void final_kernel(
    const float* __restrict__ xd, const float* __restrict__ g32,
    const u16* __restrict__ r5nk, const void* __restrict__ clsw,
    const void* __restrict__ clsb, const int* __restrict__ flag,
    void* __restrict__ outbase, int elem_off)
{
  __shared__ float xc[196];
  __shared__ float red[8];
  const int isbf = *flag;
  int b = blockIdx.x, t = threadIdx.x;
  if (t < 196){
    float s = 0;
    const float* row = xd + ((size_t)b * 196 + t) * 128;
    #pragma unroll
    for (int j = 0; j < 32; j++) s += row[j] * g32[b * 8 + (j >> 2)];
    xc[t] = s * (1.f / 32.f);
  }
  if (t < 8) red[t] = 0.f;
  __syncthreads();
  float s1[8], s2[8];
  #pragma unroll
  for (int ci = 0; ci < 8; ci++){ s1[ci] = 0.f; s2[ci] = 0.f; }
  for (int hv = 0; hv < 196; hv++){
    const u16* row = r5nk + ((size_t)b * 196 + hv) * 2048;
    float xcv = xc[hv];
    #pragma unroll
    for (int ci = 0; ci < 8; ci++){
      float v = b2f(row[t + ci * 256]);
      s1[ci] += v; s2[ci] += v * xcv;
    }
  }
  float pm[8];
  #pragma unroll
  for (int m = 0; m < 8; m++) pm[m] = 0.f;
  #pragma unroll
  for (int ci = 0; ci < 8; ci++){
    int c = t + ci * 256;
    float a1 = s1[ci] * (1.f / 196.f), a2 = s2[ci] * (1.f / 196.f);
    #pragma unroll
    for (int m = 0; m < 8; m++)
      pm[m] += inld(clsw, m * 4096 + c, isbf) * a1 + inld(clsw, m * 4096 + 2048 + c, isbf) * a2;
  }
  #pragma unroll
  for (int m = 0; m < 8; m++) atomicAdd(&red[m], pm[m]);
  __syncthreads();
  if (t < 8){
    float v = red[t] + inld(clsb, t, isbf);
    int o = elem_off + b * 8 + t;
    if (isbf) ((u16*)outbase)[o] = f2b(v);
    else      ((float*)outbase)[o] = v;
  }
}

extern "C" void kernel_launch(void* const* d_in, const int* in_sizes, int n_in,
                              void* d_out, int out_size, void* d_ws, size_t ws_size,
                              hipStream_t stream)
{
  (void)in_sizes; (void)n_in; (void)out_size;
  const void* r5  = d_in[0];
  const void* fcw = d_in[1];
  const void* bng = d_in[2];
  const void* bnb = d_in[3];
  const void* bnm = d_in[4];
  const void* bnv = d_in[5];
  const void* mu0 = d_in[6];
  const void* w4  = d_in[7];
  const void* b4  = d_in[8];
  const void* dw  = d_in[9];
  const void* db  = d_in[10];
  const void* cw  = d_in[11];
  const void* cb  = d_in[12];

  // ---- choose batches-per-pass from ws_size ----
  auto foot = [](int nb)->size_t{
    return 42ull * 1024 * 1024 + (size_t)nb * 3670016ull;
  };
  int NB = 4;
  if (foot(64) <= ws_size) NB = 64;
  else if (foot(32) <= ws_size) NB = 32;
  else if (foot(16) <= ws_size) NB = 16;
  else if (foot(8) <= ws_size) NB = 8;
  const int rowsP = NB * 196;
  const int tiles = (rowsP + 127) / 128;
  const int passes = 64 / NB;

  char* base = (char*)d_ws;
  size_t off = 0;
  auto take = [&](size_t bytes)->char*{
    char* r = base + off;
    off = (off + bytes + 255) & ~(size_t)255;
    return r;
  };

  int*   flag = (int*)  take(256);
  float* scale= (float*)take(512 * 4);
  float* bias = (float*)take(512 * 4);
  float* dbp  = (float*)take(128 * 4);
  u16*   zrow = (u16*)  take(2048 * 2);
  u16*   b4c  = (u16*)  take(2048 * 2);
  float* g32  = (float*)take(64 * 8 * 4);
  u16*   dwp  = (u16*)  take(128 * 2048 * 2);
  float* zg   = (float*)take(64ULL * 1568 * 4);
  u16*   Wt   = (u16*)  take(512ULL * 18432 * 2);          // conv3x3 weights, packed
  u16*   w4c  = (u16*)  take(2048ULL * 4096 * 2);          // conv4 weights, canonical bf16
  u16*   r5nk = (u16*)  take((size_t)rowsP * 2048 * 2);    // per-pass [n, c]
  u16*   regX = (u16*)  take((size_t)rowsP * 4096 * 2);    // x1 -> c2
  u16*   bufC = (u16*)  take((size_t)rowsP * 2048 * 2);    // xnk -> xbA
  u16*   x2b  = (u16*)  take((size_t)rowsP * 512 * 2);
  float* xd   = (float*)take((size_t)rowsP * 128 * 4);

  u16* x1  = regX;
  u16* c2  = regX;
  u16* xnk = bufC;
  u16* xbA = bufC;

  detect_kernel<<<1, 256, 0, stream>>>((const u32*)r5, flag);
  prep_kernel<<<1024, 256, 0, stream>>>(bng, bnb, bnm, bnv, dw, db, b4, flag,
                                        scale, bias, dwp, dbp, b4c, zrow);
  wt_pack<<<(512 * 18432 + 255) / 256, 256, 0, stream>>>(fcw, flag, Wt);
  cvt_w4<<<(2048 * 4096) / 256, 256, 0, stream>>>(w4, flag, w4c);

  for (int p = 0; p < passes; p++){
    size_t r5off = (size_t)p * NB * 2048 * 196;
    int oxg = p * NB * 8;
    int oo2 = 512 + p * NB * 8;

    transpose_r5<<<NB * 32, 256, 0, stream>>>(r5, r5off, flag, r5nk);
    gemm_bt<0><<<dim3(tiles, 4), 256, 0, stream>>>(r5nk, nullptr, Wt, xnk, scale, bias, nullptr, zrow, 18432, 2048, rowsP);
    em_kernel<<<NB, 512, 0, stream>>>(xnk, mu0, flag, x2b, zg);
    expand_kernel<<<NB * 14, 256, 0, stream>>>(x2b, zg, x1);
    gemm_bt<1><<<dim3(16, tiles), 256, 0, stream>>>(x1, r5nk, w4c, xbA, nullptr, nullptr, b4c, zrow, 4096, 4096, rowsP);
    gemm_bt<2><<<dim3(16, tiles), 256, 0, stream>>>(xbA, r5nk, w4c, c2, nullptr, nullptr, b4c, zrow, 4096, 2048, rowsP);
    gemm_bt<3><<<dim3(tiles, 1), 256, 0, stream>>>(c2, nullptr, dwp, xd, nullptr, dbp, nullptr, zrow, 2048, 2048, rowsP);
    pool_xg<<<NB, 256, 0, stream>>>(xd, flag, g32, d_out, oxg);
    final_kernel<<<NB, 256, 0, stream>>>(xd, g32, r5nk, cw, cb, flag, d_out, oo2);
  }
}

// Round 7
// 1596.497 us; speedup vs baseline: 1.2178x; 1.0569x over previous
//
#include <hip/hip_runtime.h>
#include <hip/hip_bf16.h>

typedef unsigned short u16;
typedef unsigned int   u32;
typedef __attribute__((ext_vector_type(4))) float f32x4;
typedef __attribute__((ext_vector_type(8))) short s16x8;

__device__ __forceinline__ float b2f(u16 u){ u32 x = ((u32)u) << 16; return __builtin_bit_cast(float, x); }
__device__ __forceinline__ u16 f2b(float f){
  u32 x = __builtin_bit_cast(u32, f);
  u32 r = (x + 0x7FFFu + ((x >> 16) & 1u)) >> 16;
  return (u16)r;
}
// dual-dtype input readers: isbf=1 -> data stored as bf16, else fp32
__device__ __forceinline__ float inld(const void* p, size_t i, int isbf){
  return isbf ? b2f(((const u16*)p)[i]) : ((const float*)p)[i];
}
__device__ __forceinline__ u16 inld16(const void* p, size_t i, int isbf){
  return isbf ? ((const u16*)p)[i] : f2b(((const float*)p)[i]);
}

__device__ __forceinline__ void async16(const void* g, void* l){
  __builtin_amdgcn_global_load_lds((const __attribute__((address_space(1))) void*)g,
                                   (__attribute__((address_space(3))) void*)l, 16, 0, 0);
}

// ---------------- dtype detector: bits14-7 of u32 = exponent byte iff bf16 pair ----------------
__global__ __launch_bounds__(256) void detect_kernel(const u32* __restrict__ r5w, int* __restrict__ flag){
  __shared__ int cnt[2];
  int t = threadIdx.x;
  if (t < 2) cnt[t] = 0;
  __syncthreads();
  int inw = 0, nz = 0;
  for (int i = t; i < 16384; i += 256){
    u32 w = r5w[i];
    if (w == 0u) continue;
    u32 e = (w >> 7) & 0xFFu;
    nz++;
    if (e >= 0x58u && e <= 0x98u) inw++;
  }
  atomicAdd(&cnt[0], inw);
  atomicAdd(&cnt[1], nz);
  __syncthreads();
  if (t == 0) flag[0] = (2 * cnt[0] >= cnt[1]) ? 1 : 0;
}

// ---------------- prep: BN scale/bias, down_w pad, b4 canon, zero row ----------------
__global__ __launch_bounds__(256) void prep_kernel(
    const void* __restrict__ g, const void* __restrict__ be,
    const void* __restrict__ mn, const void* __restrict__ vr,
    const void* __restrict__ dw, const void* __restrict__ db,
    const void* __restrict__ b4, const int* __restrict__ flag,
    float* __restrict__ scale, float* __restrict__ bias,
    u16* __restrict__ dwp, float* __restrict__ dbp,
    u16* __restrict__ b4c, u16* __restrict__ zrow)
{
  const int isbf = *flag;
  int idx = blockIdx.x * 256 + threadIdx.x;
  if (idx < 512){
    float s = inld(g, idx, isbf) / sqrtf(inld(vr, idx, isbf) + 1e-5f);
    scale[idx] = s;
    bias[idx]  = inld(be, idx, isbf) - inld(mn, idx, isbf) * s;
  }
  if (idx < 128) dbp[idx] = (idx < 32) ? inld(db, idx, isbf) : 0.f;
  if (idx < 2048){
    zrow[idx] = 0;
    b4c[idx] = inld16(b4, idx, isbf);
  }
  if (idx < 128 * 2048){
    int j = idx >> 11;
    dwp[idx] = (j < 32) ? inld16(dw, idx, isbf) : (u16)0;
  }
}

// ---------------- pack fc0_w -> Wt[o, tap*2048 + i] ----------------
__global__ __launch_bounds__(256) void wt_pack(const void* __restrict__ w, const int* __restrict__ flag,
                                               u16* __restrict__ wt){
  const int isbf = *flag;
  int idx = blockIdx.x * 256 + threadIdx.x;
  if (idx >= 512 * 18432) return;
  int o = idx / 18432;
  int r = idx - o * 18432;
  int tap = r >> 11, i = r & 2047;
  wt[idx] = inld16(w, ((size_t)(o * 2048 + i)) * 9 + tap, isbf);
}

// ---------------- canonicalize conv4 weights ----------------
__global__ __launch_bounds__(256) void cvt_w4(const void* __restrict__ w4, const int* __restrict__ flag,
                                              u16* __restrict__ w4c){
  const int isbf = *flag;
  int idx = blockIdx.x * 256 + threadIdx.x;
  if (idx < 2048 * 4096) w4c[idx] = inld16(w4, idx, isbf);
}

// ---------------- transpose r5 [b,c,hw] -> r5nk [(b,hw), c] (pass-local, dual-dtype) ----------------
__global__ __launch_bounds__(256) void transpose_r5(const void* __restrict__ r5, size_t elem_off,
                                                    const int* __restrict__ flag, u16* __restrict__ r5nk){
  __shared__ u16 tile[64 * 197];
  const int isbf = *flag;
  int blk = blockIdx.x;            // NB b * 32 c-chunks
  int b = blk >> 5, c0 = (blk & 31) * 64;
  int t = threadIdx.x;
  size_t src = elem_off + ((size_t)b * 2048 + c0) * 196;
  for (int q = t; q < 64 * 196; q += 256){
    int cl = q / 196, hv = q - cl * 196;
    tile[cl * 197 + hv] = inld16(r5, src + q, isbf);
  }
  __syncthreads();
  for (int q = t; q < 64 * 196; q += 256){
    int hv = q >> 6, cl = q & 63;
    r5nk[((size_t)b * 196 + hv) * 2048 + c0 + cl] = tile[cl * 197 + hv];
  }
}

// ---------------- shared MFMA GEMM (C[n,o] = A_nk @ B[o,:]^T) ----------------
// BK=64, async16 staging, XOR k-chunk swizzle (0 bank conflicts), XCD-ownership block swizzle:
// 1-D grid, xcd = f&7, mblk = (g/OT)*8+xcd, oblk = g%OT  ->  each A-tile read by exactly 1 XCD,
// its OT consumers temporally adjacent (L2-resident); B recycles through L3 (globally hot).
// MODE 0: conv3x3  A=r5nk shifted/masked per tap, epi: scale/bias/relu -> u16, ldc=512, OT=4
// MODE 1: dic      A=x1 (ldA=4096), epi: (+b4)*r5 -> xbA u16, ldc=2048, OT=16
// MODE 2: c2       A dual: k<2048 -> xbA, else r5nk, epi: +b4 -> u16, ldc=2048, OT=16
// MODE 3: down     A=c2 (ldA=2048), epi: +bias(f32) -> float, ldc=128, OT=1
template<int MODE, int OT>
__global__ __launch_bounds__(256) void gemm_bt(
    const u16* __restrict__ Aptr, const u16* __restrict__ A2,
    const u16* __restrict__ Bw, void* __restrict__ Cout,
    const float* __restrict__ sc, const float* __restrict__ bi,
    const u16* __restrict__ bias16, const u16* __restrict__ zrow,
    int K, int ldA, int Mrows)
{
  __shared__ u16 As[128 * 64];   // 16 KB
  __shared__ u16 Bs[128 * 64];   // 16 KB
  const int f = blockIdx.x;
  const int xcd = f & 7;
  const int g = f >> 3;
  const int oo = g % OT;
  const int ms = g / OT;
  const int mblk = ms * 8 + xcd;
  const int m0 = mblk * 128;
  if (m0 >= Mrows) return;
  const int o0 = oo * 128;

  const int tid = threadIdx.x;
  const int wv = tid >> 6, ln = tid & 63;

  // staging: wave wv covers tile rows wv*32 .. wv*32+31, four calls of 8 rows each.
  // lane ln -> row sub = ln>>3; k-chunk kq = (ln&7) XOR sub (swizzle).
  const int sub = ln >> 3;
  const int kq  = (ln & 7) ^ sub;
  const int kofs = kq * 8;

  int mA[4];
  int hA[4], vA[4];
  int oB[4];
  #pragma unroll
  for (int i = 0; i < 4; i++){
    int r = m0 + wv * 32 + i * 8 + sub;
    if (r >= Mrows) r = Mrows - 1;
    mA[i] = r;
    if constexpr (MODE == 0){
      int hv = r % 196;
      hA[i] = hv / 14; vA[i] = hv - hA[i] * 14;
    }
    oB[i] = o0 + wv * 32 + i * 8 + sub;
  }

  const int wm = (wv >> 1) * 64, wn = (wv & 1) * 64;
  const int fl = ln & 15, fq = ln >> 4;
  const int fl7 = fl & 7;

  f32x4 acc[4][4];
  #pragma unroll
  for (int i = 0; i < 4; i++)
    #pragma unroll
    for (int j = 0; j < 4; j++) acc[i][j] = (f32x4){0.f, 0.f, 0.f, 0.f};

  for (int k0 = 0; k0 < K; k0 += 64){
    #pragma unroll
    for (int i = 0; i < 4; i++){
      const u16* ga;
      if constexpr (MODE == 0){
        int tap = k0 >> 11;
        int kin = (k0 & 2047) + kofs;
        int dy = tap / 3 - 1, dx = tap - (tap / 3) * 3 - 1;
        int dlt = dy * 14 + dx;
        bool ok = ((unsigned)(hA[i] + dy) < 14u) && ((unsigned)(vA[i] + dx) < 14u);
        ga = ok ? Aptr + (size_t)(mA[i] + dlt) * 2048 + kin : zrow + kofs;
      } else if constexpr (MODE == 2){
        const u16* base = (k0 < 2048) ? Aptr : A2;
        int kin = (k0 & 2047) + kofs;
        ga = base + (size_t)mA[i] * 2048 + kin;
      } else {
        ga = Aptr + (size_t)mA[i] * ldA + k0 + kofs;
      }
      async16(ga, &As[wv * 2048 + i * 512]);
    }
    #pragma unroll
    for (int i = 0; i < 4; i++){
      const u16* gb = Bw + (size_t)oB[i] * K + k0 + kofs;
      async16(gb, &Bs[wv * 2048 + i * 512]);
    }
    __syncthreads();   // drains vmcnt -> LDS tiles complete & visible

    #pragma unroll
    for (int s = 0; s < 2; s++){
      const int pos = ((fq + 4 * s) ^ fl7) * 8;
      s16x8 af[4], bfr[4];
      #pragma unroll
      for (int i = 0; i < 4; i++)
        af[i] = *(const s16x8*)&As[(wm + i * 16 + fl) * 64 + pos];
      #pragma unroll
      for (int j = 0; j < 4; j++)
        bfr[j] = *(const s16x8*)&Bs[(wn + j * 16 + fl) * 64 + pos];
      #pragma unroll
      for (int i = 0; i < 4; i++)
        #pragma unroll
        for (int j = 0; j < 4; j++)
          acc[i][j] = __builtin_amdgcn_mfma_f32_16x16x32_bf16(af[i], bfr[j], acc[i][j], 0, 0, 0);
    }
    __syncthreads();   // all reads done before next stage overwrites LDS
  }

  #pragma unroll
  for (int i = 0; i < 4; i++){
    int mrow = m0 + wm + i * 16 + fq * 4;
    #pragma unroll
    for (int j = 0; j < 4; j++){
      int o = o0 + wn + j * 16 + fl;
      f32x4 a = acc[i][j];
      #pragma unroll
      for (int r = 0; r < 4; r++){
        int n = mrow + r;
        if (n >= Mrows) continue;
        float v = a[r];
        if constexpr (MODE == 0){
          v = fmaxf(v * sc[o] + bi[o], 0.f);
          ((u16*)Cout)[(size_t)n * 512 + o] = f2b(v);
        } else if constexpr (MODE == 1){
          v += b2f(bias16[o]);
          v *= b2f(A2[(size_t)n * 2048 + o]);
          ((u16*)Cout)[(size_t)n * 2048 + o] = f2b(v);
        } else if constexpr (MODE == 2){
          v += b2f(bias16[o]);
          ((u16*)Cout)[(size_t)n * 2048 + o] = f2b(v);
        } else {
          ((float*)Cout)[(size_t)n * 128 + o] = v + bi[o];
        }
      }
    }
  }
}

// ---------------- EM attention: one block per (pass-local) batch ----------------
__global__ __launch_bounds__(512) void em_kernel(
    const u16* __restrict__ x, const void* __restrict__ mu0, const int* __restrict__ flag,
    u16* __restrict__ x2, float* __restrict__ zg)
{
  __shared__ float mu[512][9];     // pad 8->9: conflict-free column access
  __shared__ float zz[196][9];
  __shared__ float part[64][8];
  __shared__ float red8[8];
  const int isbf = *flag;
  const int b = blockIdx.x;
  const int t = threadIdx.x;
  const u16* xb = x + (size_t)b * 196 * 512;

  for (int q = t; q < 4096; q += 512) mu[q >> 3][q & 7] = inld(mu0, q, isbf);
  __syncthreads();
  { int k = t & 7, g = t >> 3; float s = 0;
    for (int c = g; c < 512; c += 64){ float m = mu[c][k]; s += m * m; }
    part[g][k] = s; }
  __syncthreads();
  if (t < 8){ float s = 0; for (int g = 0; g < 64; g++) s += part[g][t]; red8[t] = sqrtf(s) + 1e-6f; }
  __syncthreads();
  for (int q = t; q < 4096; q += 512) mu[q >> 3][q & 7] /= red8[q & 7];
  __syncthreads();

  for (int it = 0; it < 3; it++){
    for (int p = t; p < 1568; p += 512){
      int n = p >> 3, k = p & 7;
      const u16* xr = xb + n * 512;
      float s = 0;
      for (int c = 0; c < 512; c += 8){
        uint4 u = *(const uint4*)(xr + c);
        s += b2f((u16)(u.x & 0xffff)) * mu[c][k]     + b2f((u16)(u.x >> 16)) * mu[c + 1][k]
           + b2f((u16)(u.y & 0xffff)) * mu[c + 2][k] + b2f((u16)(u.y >> 16)) * mu[c + 3][k]
           + b2f((u16)(u.z & 0xffff)) * mu[c + 4][k] + b2f((u16)(u.z >> 16)) * mu[c + 5][k]
           + b2f((u16)(u.w & 0xffff)) * mu[c + 6][k] + b2f((u16)(u.w >> 16)) * mu[c + 7][k];
      }
      zz[n][k] = s;
    }
    __syncthreads();
    if (t < 196){
      float mx = zz[t][0];
      #pragma unroll
      for (int k = 1; k < 8; k++) mx = fmaxf(mx, zz[t][k]);
      float e[8], sm = 0;
      #pragma unroll
      for (int k = 0; k < 8; k++){ e[k] = expf(zz[t][k] - mx); sm += e[k]; }
      #pragma unroll
      for (int k = 0; k < 8; k++) zz[t][k] = e[k] / sm;
    }
    __syncthreads();
    { int k = t & 7, g = t >> 3; float s = 0;
      for (int n = g; n < 196; n += 64) s += zz[n][k];
      part[g][k] = s; }
    __syncthreads();
    if (t < 8){ float s = 0; for (int g = 0; g < 64; g++) s += part[g][t]; red8[t] = s + 1e-6f; }
    __syncthreads();
    {
      int c = t;
      float s[8];
      #pragma unroll
      for (int k = 0; k < 8; k++) s[k] = 0.f;
      for (int n = 0; n < 196; n++){
        float xv = b2f(xb[n * 512 + c]);
        #pragma unroll
        for (int k = 0; k < 8; k++) s[k] += xv * zz[n][k];
      }
      __syncthreads();
      #pragma unroll
      for (int k = 0; k < 8; k++) mu[c][k] = s[k] / red8[k];
    }
    __syncthreads();
    { int k = t & 7, g = t >> 3; float s = 0;
      for (int c = g; c < 512; c += 64){ float m = mu[c][k]; s += m * m; }
      part[g][k] = s; }
    __syncthreads();
    if (t < 8){ float s = 0; for (int g = 0; g < 64; g++) s += part[g][t]; red8[t] = sqrtf(s) + 1e-6f; }
    __syncthreads();
    for (int q = t; q < 4096; q += 512) mu[q >> 3][q & 7] /= red8[q & 7];
    __syncthreads();
  }

  for (int p = t; p < 1568; p += 512) zg[b * 1568 + p] = zz[p >> 3][p & 7];
  for (int q = t; q < 196 * 512; q += 512){
    int n = q >> 9, c = q & 511;
    float xr = 0;
    #pragma unroll
    for (int k = 0; k < 8; k++) xr += mu[c][k] * zz[n][k];
    float v = b2f(xb[n * 512 + c]) + xr;
    x2[(size_t)b * 196 * 512 + q] = f2b(fmaxf(v, 0.f));
  }
}

// ---------------- expand: x1[n, k*512+c] = sum_w x2 * z_t ----------------
__global__ __launch_bounds__(256) void expand_kernel(
    const u16* __restrict__ x2, const float* __restrict__ zg, u16* __restrict__ x1)
{
  __shared__ u16 xs[14 * 512];
  __shared__ float zb[196 * 8];
  int bh = blockIdx.x;          // NB*14
  int b = bh / 14, h = bh - b * 14;
  int t = threadIdx.x;
  const u16* src = x2 + ((size_t)b * 196 + h * 14) * 512;
  for (int q = t; q < 14 * 512; q += 256) xs[q] = src[q];
  for (int q = t; q < 1568; q += 256) zb[q] = zg[b * 1568 + q];
  __syncthreads();
  size_t outbase = ((size_t)b * 196 + h * 14) * 4096;
  for (int q = t; q < 14 * 4096; q += 256){
    int v = q >> 12, kc = q & 4095;
    int k = kc >> 9, c = kc & 511;
    float s = 0;
    #pragma unroll
    for (int w = 0; w < 14; w++)
      s += b2f(xs[w * 512 + c]) * zb[(w * 14 + v) * 8 + k];
    x1[outbase + q] = f2b(s);
  }
}

// ---------------- pooling: xg (dual-dtype output) ----------------
__global__ __launch_bounds__(256) void pool_xg(
    const float* __restrict__ xd, const int* __restrict__ flag,
    float* __restrict__ g32, void* __restrict__ outbase, int elem_off)
{
  __shared__ float part[8][32];
  int b = blockIdx.x, t = threadIdx.x;
  int j = t & 31, g = t >> 5;
  float s = 0;
  for (int hv = g; hv < 196; hv += 8)
    s += xd[((size_t)b * 196 + hv) * 128 + j];
  part[g][j] = s;
  __syncthreads();
  if (t < 32){
    float s2 = 0;
    #pragma unroll
    for (int g2 = 0; g2 < 8; g2++) s2 += part[g2][t];
    part[0][t] = s2 * (1.f / 196.f);
  }
  __syncthreads();
  if (t < 8){
    float v = 0.25f * (part[0][4 * t] + part[0][4 * t + 1] + part[0][4 * t + 2] + part[0][4 * t + 3]);
    g32[b * 8 + t] = v;
    int o = elem_off + b * 8 + t;
    if (*flag) ((u16*)outbase)[o] = f2b(v);
    else       ((float*)outbase)[o] = v;
  }
}

// ---------------- final: xc, GAPs, classifier (dual-dtype in/out) ----------------
__global__ __launch_bounds__(256) void final_kernel(
    const float* __restrict__ xd, const float* __restrict__ g32,
    const u16* __restrict__ r5nk, const void* __restrict__ clsw,
    const void* __restrict__ clsb, const int* __restrict__ flag,
    void* __restrict__ outbase, int elem_off)
{
  __shared__ float xc[196];
  __shared__ float red[8];
  const int isbf = *flag;
  int b = blockIdx.x, t = threadIdx.x;
  if (t < 196){
    float s = 0;
    const float* row = xd + ((size_t)b * 196 + t) * 128;
    #pragma unroll
    for (int j = 0; j < 32; j++) s += row[j] * g32[b * 8 + (j >> 2)];
    xc[t] = s * (1.f / 32.f);
  }
  if (t < 8) red[t] = 0.f;
  __syncthreads();
  float s1[8], s2[8];
  #pragma unroll
  for (int ci = 0; ci < 8; ci++){ s1[ci] = 0.f; s2[ci] = 0.f; }
  for (int hv = 0; hv < 196; hv++){
    const u16* row = r5nk + ((size_t)b * 196 + hv) * 2048;
    float xcv = xc[hv];
    #pragma unroll
    for (int ci = 0; ci < 8; ci++){
      float v = b2f(row[t + ci * 256]);
      s1[ci] += v; s2[ci] += v * xcv;
    }
  }
  float pm[8];
  #pragma unroll
  for (int m = 0; m < 8; m++) pm[m] = 0.f;
  #pragma unroll
  for (int ci = 0; ci < 8; ci++){
    int c = t + ci * 256;
    float a1 = s1[ci] * (1.f / 196.f), a2 = s2[ci] * (1.f / 196.f);
    #pragma unroll
    for (int m = 0; m < 8; m++)
      pm[m] += inld(clsw, m * 4096 + c, isbf) * a1 + inld(clsw, m * 4096 + 2048 + c, isbf) * a2;
  }
  #pragma unroll
  for (int m = 0; m < 8; m++) atomicAdd(&red[m], pm[m]);
  __syncthreads();
  if (t < 8){
    float v = red[t] + inld(clsb, t, isbf);
    int o = elem_off + b * 8 + t;
    if (isbf) ((u16*)outbase)[o] = f2b(v);
    else      ((float*)outbase)[o] = v;
  }
}

extern "C" void kernel_launch(void* const* d_in, const int* in_sizes, int n_in,
                              void* d_out, int out_size, void* d_ws, size_t ws_size,
                              hipStream_t stream)
{
  (void)in_sizes; (void)n_in; (void)out_size;
  const void* r5  = d_in[0];
  const void* fcw = d_in[1];
  const void* bng = d_in[2];
  const void* bnb = d_in[3];
  const void* bnm = d_in[4];
  const void* bnv = d_in[5];
  const void* mu0 = d_in[6];
  const void* w4  = d_in[7];
  const void* b4  = d_in[8];
  const void* dw  = d_in[9];
  const void* db  = d_in[10];
  const void* cw  = d_in[11];
  const void* cb  = d_in[12];

  // ---- choose batches-per-pass from ws_size ----
  auto foot = [](int nb)->size_t{
    return 42ull * 1024 * 1024 + (size_t)nb * 3670016ull;
  };
  int NB = 4;
  if (foot(64) <= ws_size) NB = 64;
  else if (foot(32) <= ws_size) NB = 32;
  else if (foot(16) <= ws_size) NB = 16;
  else if (foot(8) <= ws_size) NB = 8;
  const int rowsP = NB * 196;
  const int tiles = (rowsP + 127) / 128;
  const int mchunks = (tiles + 7) / 8;
  const int passes = 64 / NB;

  char* base = (char*)d_ws;
  size_t off = 0;
  auto take = [&](size_t bytes)->char*{
    char* r = base + off;
    off = (off + bytes + 255) & ~(size_t)255;
    return r;
  };

  int*   flag = (int*)  take(256);
  float* scale= (float*)take(512 * 4);
  float* bias = (float*)take(512 * 4);
  float* dbp  = (float*)take(128 * 4);
  u16*   zrow = (u16*)  take(2048 * 2);
  u16*   b4c  = (u16*)  take(2048 * 2);
  float* g32  = (float*)take(64 * 8 * 4);
  u16*   dwp  = (u16*)  take(128 * 2048 * 2);
  float* zg   = (float*)take(64ULL * 1568 * 4);
  u16*   Wt   = (u16*)  take(512ULL * 18432 * 2);          // conv3x3 weights, packed
  u16*   w4c  = (u16*)  take(2048ULL * 4096 * 2);          // conv4 weights, canonical bf16
  u16*   r5nk = (u16*)  take((size_t)rowsP * 2048 * 2);    // per-pass [n, c]
  u16*   regX = (u16*)  take((size_t)rowsP * 4096 * 2);    // x1 -> c2
  u16*   bufC = (u16*)  take((size_t)rowsP * 2048 * 2);    // xnk -> xbA
  u16*   x2b  = (u16*)  take((size_t)rowsP * 512 * 2);
  float* xd   = (float*)take((size_t)rowsP * 128 * 4);

  u16* x1  = regX;
  u16* c2  = regX;
  u16* xnk = bufC;
  u16* xbA = bufC;

  detect_kernel<<<1, 256, 0, stream>>>((const u32*)r5, flag);
  prep_kernel<<<1024, 256, 0, stream>>>(bng, bnb, bnm, bnv, dw, db, b4, flag,
                                        scale, bias, dwp, dbp, b4c, zrow);
  wt_pack<<<(512 * 18432 + 255) / 256, 256, 0, stream>>>(fcw, flag, Wt);
  cvt_w4<<<(2048 * 4096) / 256, 256, 0, stream>>>(w4, flag, w4c);

  for (int p = 0; p < passes; p++){
    size_t r5off = (size_t)p * NB * 2048 * 196;
    int oxg = p * NB * 8;
    int oo2 = 512 + p * NB * 8;

    transpose_r5<<<NB * 32, 256, 0, stream>>>(r5, r5off, flag, r5nk);
    gemm_bt<0, 4><<<8 * 4 * mchunks, 256, 0, stream>>>(r5nk, nullptr, Wt, xnk, scale, bias, nullptr, zrow, 18432, 2048, rowsP);
    em_kernel<<<NB, 512, 0, stream>>>(xnk, mu0, flag, x2b, zg);
    expand_kernel<<<NB * 14, 256, 0, stream>>>(x2b, zg, x1);
    gemm_bt<1, 16><<<8 * 16 * mchunks, 256, 0, stream>>>(x1, r5nk, w4c, xbA, nullptr, nullptr, b4c, zrow, 4096, 4096, rowsP);
    gemm_bt<2, 16><<<8 * 16 * mchunks, 256, 0, stream>>>(xbA, r5nk, w4c, c2, nullptr, nullptr, b4c, zrow, 4096, 2048, rowsP);
    gemm_bt<3, 1><<<8 * 1 * mchunks, 256, 0, stream>>>(c2, nullptr, dwp, xd, nullptr, dbp, nullptr, zrow, 2048, 2048, rowsP);
    pool_xg<<<NB, 256, 0, stream>>>(xd, flag, g32, d_out, oxg);
    final_kernel<<<NB, 256, 0, stream>>>(xd, g32, r5nk, cw, cb, flag, d_out, oo2);
  }
}